// Round 10
// baseline (196.175 us; speedup 1.0000x reference)
//
#include <hip/hip_runtime.h>
#include <hip/hip_bf16.h>
#include <math.h>

// Problem constants
#define NN 768
#define CS 256
#define CZ 128
#define CH 128
#define HH 8
#define PQK 8
#define PV 12
#define CONCAT 2432   // 1024 + 288 + 96 + 1024
#define ATT_HSTRIDE (768*768)

typedef __bf16 v8bf __attribute__((ext_vector_type(8)));
typedef __bf16 v4bf __attribute__((ext_vector_type(4)));
typedef float  v4f  __attribute__((ext_vector_type(4)));

__device__ inline unsigned short f2bf(float f) {
    union { float f; unsigned u; } v; v.f = f;
    unsigned r = v.u + 0x7FFFu + ((v.u >> 16) & 1u);
    return (unsigned short)(r >> 16);
}
__device__ inline float bf2f(unsigned short u) {
    union { unsigned u; float f; } v; v.u = ((unsigned)u) << 16; return v.f;
}
// order-preserving float<->uint encoding (for atomicMax on floats)
__device__ inline unsigned encf(float f) {
    unsigned u = __float_as_uint(f);
    return (u >> 31) ? ~u : (u | 0x80000000u);
}
__device__ inline float decf(unsigned e) {
    unsigned u = (e >> 31) ? (e & 0x7FFFFFFFu) : ~e;
    return __uint_as_float(u);
}
__device__ inline v8bf cvt8(const float* p) {
    float4 a = *(const float4*)p;
    float4 b = *(const float4*)(p + 4);
    v8bf v;
    v[0] = (__bf16)a.x; v[1] = (__bf16)a.y; v[2] = (__bf16)a.z; v[3] = (__bf16)a.w;
    v[4] = (__bf16)b.x; v[5] = (__bf16)b.y; v[6] = (__bf16)b.z; v[7] = (__bf16)b.w;
    return v;
}

// ---------------------------------------------------------------------------
// Combined projection GEMM: 4 weight segments, shared A = s (f32, inline cvt).
// ---------------------------------------------------------------------------
struct ProjDesc {
    const float* W[4];
    const float* bias[4];
    unsigned short* dstb[4];
    float* dstf[4];
    int D[4];
    int ldc[4];
    int mode[4];
    int blk_start[5];
};

__global__ __launch_bounds__(256) void proj_all(const float* __restrict__ S, ProjDesc d)
{
    __shared__ unsigned short As[64][40];
    __shared__ unsigned short Ws[64][40];
    int bx = blockIdx.x;
    int seg = 0;
    #pragma unroll
    for (int q = 0; q < 3; q++) if (bx >= d.blk_start[q + 1]) seg = q + 1;
    int bd = (bx - d.blk_start[seg]) * 64;
    int bi = blockIdx.y * 64;
    const float* W = d.W[seg];
    int D = d.D[seg], ldc = d.ldc[seg];

    int tid = threadIdx.x, lane = tid & 63, wid = tid >> 6;
    int wr = (wid >> 1) * 32, wc = (wid & 1) * 32;
    v4f acc[2][2] = {};
    int lrow = tid >> 2, lcol = (tid & 3) * 8;
    const float* Ap = S + (size_t)(bi + lrow) * 256 + lcol;
    const float* Wp = W + (size_t)(bd + lrow) * 256 + lcol;
    bool wv = (bd + lrow) < D;
    int fr = lane & 15, fc = (lane >> 4) * 8;

    for (int k0 = 0; k0 < 256; k0 += 32) {
        *(v8bf*)&As[lrow][lcol] = cvt8(Ap + k0);
        v8bf wz = {};
        *(v8bf*)&Ws[lrow][lcol] = wv ? cvt8(Wp + k0) : wz;
        __syncthreads();
        v8bf a0 = *(const v8bf*)&As[wr + fr][fc];
        v8bf a1 = *(const v8bf*)&As[wr + 16 + fr][fc];
        v8bf b0 = *(const v8bf*)&Ws[wc + fr][fc];
        v8bf b1 = *(const v8bf*)&Ws[wc + 16 + fr][fc];
        acc[0][0] = __builtin_amdgcn_mfma_f32_16x16x32_bf16(a0, b0, acc[0][0], 0, 0, 0);
        acc[0][1] = __builtin_amdgcn_mfma_f32_16x16x32_bf16(a0, b1, acc[0][1], 0, 0, 0);
        acc[1][0] = __builtin_amdgcn_mfma_f32_16x16x32_bf16(a1, b0, acc[1][0], 0, 0, 0);
        acc[1][1] = __builtin_amdgcn_mfma_f32_16x16x32_bf16(a1, b1, acc[1][1], 0, 0, 0);
        __syncthreads();
    }
    const float* bias = d.bias[seg];
    int mode = d.mode[seg];
    unsigned short* Cb = d.dstb[seg];
    float* Cf = d.dstf[seg];
    int mrow = (lane >> 4) * 4;
    #pragma unroll
    for (int mi = 0; mi < 2; mi++) {
        #pragma unroll
        for (int ni = 0; ni < 2; ni++) {
            int dd = bd + wc + ni * 16 + fr;
            if (dd < D) {
                #pragma unroll
                for (int r = 0; r < 4; r++) {
                    int m = bi + wr + mi * 16 + mrow + r;
                    float v = acc[mi][ni][r] + bias[dd];
                    if (mode == 2) Cb[(size_t)m * ldc + dd] = f2bf(v);
                    else           Cf[(size_t)m * ldc + dd] = v;
                }
            }
        }
    }
}

// ---------------------------------------------------------------------------
// Wo GEMM: split-K=4, A = concat (bf16), W = Wo (f32, inline cvt), atomics.
// ---------------------------------------------------------------------------
__global__ __launch_bounds__(256) void wo_gemm(
    const unsigned short* __restrict__ A,
    const float* __restrict__ W,
    float* __restrict__ C)
{
    __shared__ unsigned short As[64][40];
    __shared__ unsigned short Ws[64][40];
    const int K = 2432, ldc = 256;
    int tid = threadIdx.x;
    int bi = blockIdx.y * 64;
    int bd = blockIdx.x * 64;
    int kpb = K / 4;
    int k0b = blockIdx.z * kpb;
    int lane = tid & 63;
    int wid = tid >> 6;
    int wr = (wid >> 1) * 32, wc = (wid & 1) * 32;
    v4f acc[2][2] = {};
    int lrow = tid >> 2;
    int lcol = (tid & 3) * 8;
    const unsigned short* Ap = A + (size_t)(bi + lrow) * K + lcol;
    const float* Wp = W + (size_t)(bd + lrow) * K + lcol;
    int fr = lane & 15, fc = (lane >> 4) * 8;

    for (int k0 = k0b; k0 < k0b + kpb; k0 += 32) {
        *(int4*)&As[lrow][lcol] = *(const int4*)(Ap + k0);
        *(v8bf*)&Ws[lrow][lcol] = cvt8(Wp + k0);
        __syncthreads();
        v8bf a0 = *(const v8bf*)&As[wr + fr][fc];
        v8bf a1 = *(const v8bf*)&As[wr + 16 + fr][fc];
        v8bf b0 = *(const v8bf*)&Ws[wc + fr][fc];
        v8bf b1 = *(const v8bf*)&Ws[wc + 16 + fr][fc];
        acc[0][0] = __builtin_amdgcn_mfma_f32_16x16x32_bf16(a0, b0, acc[0][0], 0, 0, 0);
        acc[0][1] = __builtin_amdgcn_mfma_f32_16x16x32_bf16(a0, b1, acc[0][1], 0, 0, 0);
        acc[1][0] = __builtin_amdgcn_mfma_f32_16x16x32_bf16(a1, b0, acc[1][0], 0, 0, 0);
        acc[1][1] = __builtin_amdgcn_mfma_f32_16x16x32_bf16(a1, b1, acc[1][1], 0, 0, 0);
        __syncthreads();
    }
    int mrow = (lane >> 4) * 4;
    #pragma unroll
    for (int mi = 0; mi < 2; mi++) {
        #pragma unroll
        for (int ni = 0; ni < 2; ni++) {
            int d = bd + wc + ni * 16 + fr;
            #pragma unroll
            for (int r = 0; r < 4; r++) {
                int m = bi + wr + mi * 16 + mrow + r;
                atomicAdd(&C[(size_t)m * ldc + d], acc[mi][ni][r]);
            }
        }
    }
}

// ---------------------------------------------------------------------------
// prep2: rotate points (blocks < 672) + V transpose (blocks >= 672)
// ---------------------------------------------------------------------------
__global__ __launch_bounds__(256) void prep2_kernel(
    const float* __restrict__ qpraw, const float* __restrict__ kvpraw,
    const float* __restrict__ rot, const float* __restrict__ trans,
    const unsigned short* __restrict__ kv_bf,
    unsigned short* __restrict__ qph, unsigned short* __restrict__ qpl,
    unsigned short* __restrict__ kph, unsigned short* __restrict__ kpl,
    unsigned short* __restrict__ Vc)
{
    __shared__ unsigned short tile[32][136];
    int bx = blockIdx.x;
    int t = threadIdx.x;
    if (bx < 672) {
        int id = bx*256 + t;
        int i = id / (HH*28);
        int rem = id % (HH*28);
        int h = rem / 28;
        int idx = rem % 28;
        const float* R = rot + i*9;
        const float* T = trans + i*3;
        float s0, s1, s2;
        if (idx < 8) {
            s0 = qpraw[i*192 +   0 + h*8 + idx];
            s1 = qpraw[i*192 +  64 + h*8 + idx];
            s2 = qpraw[i*192 + 128 + h*8 + idx];
        } else {
            int pp = idx - 8;
            s0 = kvpraw[i*480 +   0 + h*20 + pp];
            s1 = kvpraw[i*480 + 160 + h*20 + pp];
            s2 = kvpraw[i*480 + 320 + h*20 + pp];
        }
        float ov[3];
        ov[0] = R[0]*s0 + R[1]*s1 + R[2]*s2 + T[0];
        ov[1] = R[3]*s0 + R[4]*s1 + R[5]*s2 + T[1];
        ov[2] = R[6]*s0 + R[7]*s1 + R[8]*s2 + T[2];
        if (idx < 8) {
            #pragma unroll
            for (int x = 0; x < 3; x++) {
                unsigned short hi = f2bf(ov[x]);
                qph[i*256 + h*32 + idx*3 + x] = hi;
                qpl[i*256 + h*32 + idx*3 + x] = f2bf(ov[x] - bf2f(hi));
            }
            if (idx == 0) {
                #pragma unroll
                for (int m = 24; m < 32; m++) { qph[i*256+h*32+m] = 0; qpl[i*256+h*32+m] = 0; }
            }
        } else if (idx < 16) {
            int pp = idx - 8;
            #pragma unroll
            for (int x = 0; x < 3; x++) {
                unsigned short hi = f2bf(ov[x]);
                kph[i*256 + h*32 + pp*3 + x] = hi;
                kpl[i*256 + h*32 + pp*3 + x] = f2bf(ov[x] - bf2f(hi));
            }
            if (idx == 8) {
                #pragma unroll
                for (int m = 24; m < 32; m++) { kph[i*256+h*32+m] = 0; kpl[i*256+h*32+m] = 0; }
            }
        } else {
            int ppv = idx - 16;
            #pragma unroll
            for (int x = 0; x < 3; x++)
                Vc[((size_t)h*192 + 128 + ppv*3 + x)*768 + i] = f2bf(ov[x]);
        }
    } else {
        int bx2 = bx - 672;
        int h = bx2 & 7, jt = bx2 >> 3;
        int r = t >> 3, c0 = (t & 7) * 16;
        const unsigned short* src = kv_bf + (size_t)(jt*32 + r)*2048 + h*256 + 128 + c0;
        *(int4*)&tile[r][c0]     = *(const int4*)src;
        *(int4*)&tile[r][c0 + 8] = *(const int4*)(src + 8);
        __syncthreads();
        int c = t >> 1, jh = (t & 1) * 16;
        unsigned short tmp[16];
        #pragma unroll
        for (int k = 0; k < 16; k++) tmp[k] = tile[jh + k][c];
        unsigned short* dst = Vc + ((size_t)h*192 + c)*768 + jt*32 + jh;
        *(int4*)dst       = *(int4*)&tmp[0];
        *(int4*)(dst + 8) = *(int4*)&tmp[8];
    }
}

// ---------------------------------------------------------------------------
// Logits via MFMA. Point fragments direct from global; Qss/Kss in-register.
// Row max folded in via order-encoded atomicMax.
// ---------------------------------------------------------------------------
__global__ __launch_bounds__(256) void logits_mfma(
    const unsigned short* __restrict__ q_bf, const unsigned short* __restrict__ kv_bf,
    const unsigned short* __restrict__ qph, const unsigned short* __restrict__ qpl,
    const unsigned short* __restrict__ kph, const unsigned short* __restrict__ kpl,
    const float* __restrict__ mask, const float* __restrict__ head_w,
    float* __restrict__ att, unsigned* __restrict__ m0enc)
{
    __shared__ unsigned short Qs[64][136];
    __shared__ unsigned short Ks[64][136];
    __shared__ float Mi[64], Mj[64];
    int h = blockIdx.z;
    int i0 = blockIdx.y * 64, j0 = blockIdx.x * 64;
    int tid = threadIdx.x, lane = tid & 63, wid = tid >> 6;
    int wr = (wid >> 1) * 32, wc = (wid & 1) * 32;
    int r = tid >> 2, cq = (tid & 3) * 32;
    const unsigned short* qg = q_bf  + (size_t)(i0 + r)*1024 + h*128 + cq;
    const unsigned short* kg = kv_bf + (size_t)(j0 + r)*2048 + h*256 + cq;
    #pragma unroll
    for (int kk = 0; kk < 4; kk++) {
        *(int4*)&Qs[r][cq + kk*8] = *(const int4*)(qg + kk*8);
        *(int4*)&Ks[r][cq + kk*8] = *(const int4*)(kg + kk*8);
    }
    if (tid < 64) {
        Mi[tid] = mask[i0 + tid];
        Mj[tid] = mask[j0 + tid];
    }
    int fr = lane & 15, fc = (lane >> 4) * 8;
    v8bf ah0 = *(const v8bf*)&qph[(size_t)(i0 + wr + fr)*256 + h*32 + fc];
    v8bf ah1 = *(const v8bf*)&qph[(size_t)(i0 + wr + 16 + fr)*256 + h*32 + fc];
    v8bf al0 = *(const v8bf*)&qpl[(size_t)(i0 + wr + fr)*256 + h*32 + fc];
    v8bf al1 = *(const v8bf*)&qpl[(size_t)(i0 + wr + 16 + fr)*256 + h*32 + fc];
    v8bf bh0 = *(const v8bf*)&kph[(size_t)(j0 + wc + fr)*256 + h*32 + fc];
    v8bf bh1 = *(const v8bf*)&kph[(size_t)(j0 + wc + 16 + fr)*256 + h*32 + fc];
    v8bf bl0 = *(const v8bf*)&kpl[(size_t)(j0 + wc + fr)*256 + h*32 + fc];
    v8bf bl1 = *(const v8bf*)&kpl[(size_t)(j0 + wc + 16 + fr)*256 + h*32 + fc];
    float q2a = 0.f, q2b = 0.f, k2a = 0.f, k2b = 0.f;
    #pragma unroll
    for (int m = 0; m < 8; m++) {
        float va = (float)ah0[m] + (float)al0[m];
        float vb = (float)ah1[m] + (float)al1[m];
        float wa = (float)bh0[m] + (float)bl0[m];
        float wb = (float)bh1[m] + (float)bl1[m];
        q2a += va*va; q2b += vb*vb; k2a += wa*wa; k2b += wb*wb;
    }
    q2a += __shfl_xor(q2a, 16); q2a += __shfl_xor(q2a, 32);
    q2b += __shfl_xor(q2b, 16); q2b += __shfl_xor(q2b, 32);
    k2a += __shfl_xor(k2a, 16); k2a += __shfl_xor(k2a, 32);
    k2b += __shfl_xor(k2b, 16); k2b += __shfl_xor(k2b, 32);

    v4f ap[2][2] = {};
    ap[0][0] = __builtin_amdgcn_mfma_f32_16x16x32_bf16(ah0, bh0, ap[0][0], 0, 0, 0);
    ap[0][1] = __builtin_amdgcn_mfma_f32_16x16x32_bf16(ah0, bh1, ap[0][1], 0, 0, 0);
    ap[1][0] = __builtin_amdgcn_mfma_f32_16x16x32_bf16(ah1, bh0, ap[1][0], 0, 0, 0);
    ap[1][1] = __builtin_amdgcn_mfma_f32_16x16x32_bf16(ah1, bh1, ap[1][1], 0, 0, 0);
    ap[0][0] = __builtin_amdgcn_mfma_f32_16x16x32_bf16(ah0, bl0, ap[0][0], 0, 0, 0);
    ap[0][1] = __builtin_amdgcn_mfma_f32_16x16x32_bf16(ah0, bl1, ap[0][1], 0, 0, 0);
    ap[1][0] = __builtin_amdgcn_mfma_f32_16x16x32_bf16(ah1, bl0, ap[1][0], 0, 0, 0);
    ap[1][1] = __builtin_amdgcn_mfma_f32_16x16x32_bf16(ah1, bl1, ap[1][1], 0, 0, 0);
    ap[0][0] = __builtin_amdgcn_mfma_f32_16x16x32_bf16(al0, bh0, ap[0][0], 0, 0, 0);
    ap[0][1] = __builtin_amdgcn_mfma_f32_16x16x32_bf16(al0, bh1, ap[0][1], 0, 0, 0);
    ap[1][0] = __builtin_amdgcn_mfma_f32_16x16x32_bf16(al1, bh0, ap[1][0], 0, 0, 0);
    ap[1][1] = __builtin_amdgcn_mfma_f32_16x16x32_bf16(al1, bh1, ap[1][1], 0, 0, 0);

    __syncthreads();
    v4f aqk[2][2] = {};
    #pragma unroll
    for (int ks = 0; ks < 4; ks++) {
        v8bf a0 = *(const v8bf*)&Qs[wr + fr][ks*32 + fc];
        v8bf a1 = *(const v8bf*)&Qs[wr + 16 + fr][ks*32 + fc];
        v8bf b0 = *(const v8bf*)&Ks[wc + fr][ks*32 + fc];
        v8bf b1 = *(const v8bf*)&Ks[wc + 16 + fr][ks*32 + fc];
        aqk[0][0] = __builtin_amdgcn_mfma_f32_16x16x32_bf16(a0, b0, aqk[0][0], 0, 0, 0);
        aqk[0][1] = __builtin_amdgcn_mfma_f32_16x16x32_bf16(a0, b1, aqk[0][1], 0, 0, 0);
        aqk[1][0] = __builtin_amdgcn_mfma_f32_16x16x32_bf16(a1, b0, aqk[1][0], 0, 0, 0);
        aqk[1][1] = __builtin_amdgcn_mfma_f32_16x16x32_bf16(a1, b1, aqk[1][1], 0, 0, 0);
    }
    float hx = head_w[h];
    float sp = (hx > 20.f) ? hx : log1pf(__expf(hx));
    float hw = sp * 0.09622504486493764f;
    const float scale_qk = 0.05103103630798288f;
    int mrow = (lane >> 4) * 4;
    float val[2][2][4];
    #pragma unroll
    for (int mi = 0; mi < 2; mi++) {
        #pragma unroll
        for (int rr = 0; rr < 4; rr++) {
            float qss = __shfl((mi == 0) ? q2a : q2b, mrow + rr);
            #pragma unroll
            for (int ni = 0; ni < 2; ni++) {
                int jl = wc + ni*16 + fr;
                int il = wr + mi*16 + mrow + rr;
                float kss = (ni == 0) ? k2a : k2b;
                float v = aqk[mi][ni][rr]*scale_qk + hw*ap[mi][ni][rr]
                        - 0.5f*hw*(qss + kss)
                        + 100000.0f*(Mi[il]*Mj[jl] - 1.0f);
                val[mi][ni][rr] = v;
                att[(size_t)h*ATT_HSTRIDE + (size_t)(i0 + il)*768 + (j0 + jl)] = v;
            }
        }
    }
    #pragma unroll
    for (int mi = 0; mi < 2; mi++) {
        #pragma unroll
        for (int rr = 0; rr < 4; rr++) {
            float m = fmaxf(val[mi][0][rr], val[mi][1][rr]);
            #pragma unroll
            for (int d2 = 1; d2 < 16; d2 <<= 1) m = fmaxf(m, __shfl_xor(m, d2));
            if (fr == 0) {
                int il = wr + mi*16 + mrow + rr;
                atomicMax(&m0enc[h*768 + i0 + il], encf(m));
            }
        }
    }
}

// ---------------------------------------------------------------------------
// fused_p3s: half of the j-range per block (384 j, 6 tiles); single pass over
// p; MFMA bias + MFMA opair; double-buffered ptile (2 barriers/tile).
// ---------------------------------------------------------------------------
__global__ __launch_bounds__(256) void fused_p3s_kernel(
    const float* __restrict__ att0,
    const float* __restrict__ p,
    const float* __restrict__ Wpb, const float* __restrict__ bpb,
    const unsigned* __restrict__ m0enc,
    unsigned short* __restrict__ att_bf,
    float* __restrict__ lpart,
    float* __restrict__ opart)
{
    __shared__ unsigned short ptile[2][64][132];
    __shared__ unsigned short wt[16][72];
    __shared__ float bpb_s[8], m8[8], lsum_w[4][8];

    int i = blockIdx.x;
    int half = blockIdx.y;
    int jbase = half * 384;
    int tid = threadIdx.x, lane = tid & 63, wid = tid >> 6;
    int fr = lane & 15, fc = (lane >> 4) * 8;
    int mrow = (lane >> 4) * 4;

    for (int idx = tid; idx < 16*72; idx += 256) ((unsigned short*)wt)[idx] = 0;
    if (tid < 8) {
        bpb_s[tid] = bpb[tid];
        m8[tid] = decf(m0enc[tid*768 + i]);
    }

    v8bf aW[4];
    #pragma unroll
    for (int ks = 0; ks < 4; ks++) {
        v8bf v = {};
        if (fr < 8) v = cvt8(Wpb + fr*128 + ks*32 + fc);
        aW[ks] = v;
    }

    const float* pbase = p + (size_t)i*98304 + (size_t)jbase*128;
    int ldrow = tid >> 4, ldz = (tid & 15) * 8;
    float4 pfA[4], pfB[4];
    #pragma unroll
    for (int r2 = 0; r2 < 4; r2++) {
        const float* src = pbase + (size_t)(r2*16 + ldrow)*128 + ldz;
        pfA[r2] = *(const float4*)src;
        pfB[r2] = *(const float4*)(src + 4);
    }
    #pragma unroll
    for (int r2 = 0; r2 < 4; r2++) {
        v4bf lo, hi;
        lo[0] = (__bf16)pfA[r2].x; lo[1] = (__bf16)pfA[r2].y;
        lo[2] = (__bf16)pfA[r2].z; lo[3] = (__bf16)pfA[r2].w;
        hi[0] = (__bf16)pfB[r2].x; hi[1] = (__bf16)pfB[r2].y;
        hi[2] = (__bf16)pfB[r2].z; hi[3] = (__bf16)pfB[r2].w;
        *(v4bf*)&ptile[0][r2*16 + ldrow][ldz]     = lo;
        *(v4bf*)&ptile[0][r2*16 + ldrow][ldz + 4] = hi;
    }
    #pragma unroll
    for (int r2 = 0; r2 < 4; r2++) {
        const float* src = pbase + (size_t)(64 + r2*16 + ldrow)*128 + ldz;
        pfA[r2] = *(const float4*)src;
        pfB[r2] = *(const float4*)(src + 4);
    }
    __syncthreads();
    float m0l[4];
    #pragma unroll
    for (int r2 = 0; r2 < 4; r2++) m0l[r2] = (mrow == 0) ? m8[r2] : m8[4 + r2];

    v4f accD[2] = {};
    float lacc[4] = {0.f, 0.f, 0.f, 0.f};
    const float sqrt13 = 0.57735026918962576f;
    bool expo = (mrow < 8);

    for (int t64 = 0; t64 < 6; t64++) {
        int cur = t64 & 1;
        int j0 = jbase + t64 * 64;

        v4f bd = {};
        #pragma unroll
        for (int ks = 0; ks < 4; ks++) {
            int c = ks*32 + fc;
            v4bf blo = *(const v4bf*)&ptile[cur][16*wid + fr][c];
            v4bf bhi = *(const v4bf*)&ptile[cur][16*wid + fr][c + 4];
            v8bf b;
            b[0]=blo[0]; b[1]=blo[1]; b[2]=blo[2]; b[3]=blo[3];
            b[4]=bhi[0]; b[5]=bhi[1]; b[6]=bhi[2]; b[7]=bhi[3];
            bd = __builtin_amdgcn_mfma_f32_16x16x32_bf16(aW[ks], b, bd, 0, 0, 0);
        }
        if (expo) {
            int j = 16*wid + fr;
            float a0v[4], w8[4];
            #pragma unroll
            for (int r2 = 0; r2 < 4; r2++)
                a0v[r2] = att0[((size_t)(mrow + r2)*768 + i)*768 + j0 + j];
            #pragma unroll
            for (int r2 = 0; r2 < 4; r2++) {
                int h = mrow + r2;
                float L = a0v[r2] + sqrt13*(bd[r2] + bpb_s[h]);
                w8[r2] = __expf(fminf(L - m0l[r2], 60.f));
            }
            #pragma unroll
            for (int r2 = 0; r2 < 4; r2++) {
                int h = mrow + r2;
                unsigned short wb = f2bf(w8[r2]);
                wt[h][j] = wb;
                att_bf[((size_t)h*768 + i)*768 + j0 + j] = wb;
            }
            #pragma unroll
            for (int m = 1; m < 16; m <<= 1) {
                #pragma unroll
                for (int r2 = 0; r2 < 4; r2++) w8[r2] += __shfl_xor(w8[r2], m);
            }
            #pragma unroll
            for (int r2 = 0; r2 < 4; r2++) lacc[r2] += w8[r2];
        }
        if (t64 < 5) {
            #pragma unroll
            for (int r2 = 0; r2 < 4; r2++) {
                v4bf lo, hi;
                lo[0] = (__bf16)pfA[r2].x; lo[1] = (__bf16)pfA[r2].y;
                lo[2] = (__bf16)pfA[r2].z; lo[3] = (__bf16)pfA[r2].w;
                hi[0] = (__bf16)pfB[r2].x; hi[1] = (__bf16)pfB[r2].y;
                hi[2] = (__bf16)pfB[r2].z; hi[3] = (__bf16)pfB[r2].w;
                *(v4bf*)&ptile[cur ^ 1][r2*16 + ldrow][ldz]     = lo;
                *(v4bf*)&ptile[cur ^ 1][r2*16 + ldrow][ldz + 4] = hi;
            }
            if (t64 < 4) {
                #pragma unroll
                for (int r2 = 0; r2 < 4; r2++) {
                    const float* src = pbase + (size_t)((t64+2)*64 + r2*16 + ldrow)*128 + ldz;
                    pfA[r2] = *(const float4*)src;
                    pfB[r2] = *(const float4*)(src + 4);
                }
            }
        }
        __syncthreads();

        #pragma unroll
        for (int mm = 0; mm < 2; mm++) {
            int zcol = (2*wid + mm)*16 + fr;
            #pragma unroll
            for (int ks = 0; ks < 2; ks++) {
                v8bf b;
                #pragma unroll
                for (int kk = 0; kk < 8; kk++)
                    b[kk] = *(const __bf16*)&ptile[cur][ks*32 + fc + kk][zcol];
                v8bf a = *(const v8bf*)&wt[fr][ks*32 + fc];
                accD[mm] = __builtin_amdgcn_mfma_f32_16x16x32_bf16(a, b, accD[mm], 0, 0, 0);
            }
        }
        __syncthreads();
    }

    if (fr == 0 && expo) {
        #pragma unroll
        for (int r2 = 0; r2 < 4; r2++) lsum_w[wid][mrow + r2] = lacc[r2];
    }
    __syncthreads();
    if (tid < 8) {
        lpart[(size_t)(half*8 + tid)*768 + i] =
            lsum_w[0][tid] + lsum_w[1][tid] + lsum_w[2][tid] + lsum_w[3][tid];
    }
    if (expo) {
        float* ob = opart + (size_t)(half*768 + i)*1024;
        #pragma unroll
        for (int mm = 0; mm < 2; mm++) {
            int z = (2*wid + mm)*16 + fr;
            #pragma unroll
            for (int r2 = 0; r2 < 4; r2++)
                ob[(mrow + r2)*128 + z] = accD[mm][r2];
        }
    }
}

// ---------------------------------------------------------------------------
// preduce: sum the two j-half partials -> linv + opair into concat
// ---------------------------------------------------------------------------
__global__ __launch_bounds__(256) void preduce_kernel(
    const float* __restrict__ lpart, const float* __restrict__ opart,
    float* __restrict__ linv, unsigned short* __restrict__ concat)
{
    __shared__ float inv_s[8];
    int i = blockIdx.x, t = threadIdx.x;
    if (t < 8) {
        float l = lpart[(size_t)t*768 + i] + lpart[(size_t)(8 + t)*768 + i];
        float iv = 1.0f / l;
        inv_s[t] = iv;
        linv[(size_t)t*768 + i] = iv;
    }
    __syncthreads();
    const float* o0 = opart + (size_t)i*1024;
    const float* o1 = opart + (size_t)(768 + i)*1024;
    #pragma unroll
    for (int k = 0; k < 4; k++) {
        int c = t + k*256;
        float s = o0[c] + o1[c];
        concat[(size_t)i*CONCAT + 1408 + c] = f2bf(s * inv_s[c >> 7]);
    }
}

// ---------------------------------------------------------------------------
// Fused (o | opt) = (att_unnorm @ Vc^T) * linv per h; opt blocks also do
// rot^T/trans/norm epilogue.
// ---------------------------------------------------------------------------
__global__ __launch_bounds__(256) void attvc_mfma(
    const unsigned short* __restrict__ att_bf, const unsigned short* __restrict__ Vc,
    const float* __restrict__ linv, const float* __restrict__ rot,
    const float* __restrict__ trans, unsigned short* __restrict__ concat)
{
    __shared__ unsigned short As[64][72];
    __shared__ unsigned short Bs[64][72];
    int h = blockIdx.z;
    int i0 = blockIdx.y * 64, nd0 = blockIdx.x * 64;
    int tid = threadIdx.x, lane = tid & 63, wid = tid >> 6;
    int wr = (wid >> 1) * 32, wc = (wid & 1) * 32;
    int r = tid >> 2, c8 = (tid & 3) * 16;
    int fr = lane & 15, fc = (lane >> 4) * 8;
    v4f acc[2][2] = {};
    for (int k0 = 0; k0 < 768; k0 += 64) {
        const unsigned short* ag = att_bf + ((size_t)h*768 + i0 + r)*768 + k0 + c8;
        const unsigned short* bg = Vc + ((size_t)h*192 + nd0 + r)*768 + k0 + c8;
        *(int4*)&As[r][c8]     = *(const int4*)ag;
        *(int4*)&As[r][c8 + 8] = *(const int4*)(ag + 8);
        *(int4*)&Bs[r][c8]     = *(const int4*)bg;
        *(int4*)&Bs[r][c8 + 8] = *(const int4*)(bg + 8);
        __syncthreads();
        #pragma unroll
        for (int ks = 0; ks < 2; ks++) {
            v8bf a0 = *(const v8bf*)&As[wr + fr][ks*32 + fc];
            v8bf a1 = *(const v8bf*)&As[wr + 16 + fr][ks*32 + fc];
            v8bf b0 = *(const v8bf*)&Bs[wc + fr][ks*32 + fc];
            v8bf b1 = *(const v8bf*)&Bs[wc + 16 + fr][ks*32 + fc];
            acc[0][0] = __builtin_amdgcn_mfma_f32_16x16x32_bf16(a0, b0, acc[0][0], 0, 0, 0);
            acc[0][1] = __builtin_amdgcn_mfma_f32_16x16x32_bf16(a0, b1, acc[0][1], 0, 0, 0);
            acc[1][0] = __builtin_amdgcn_mfma_f32_16x16x32_bf16(a1, b0, acc[1][0], 0, 0, 0);
            acc[1][1] = __builtin_amdgcn_mfma_f32_16x16x32_bf16(a1, b1, acc[1][1], 0, 0, 0);
        }
        __syncthreads();
    }
    int mrow = (lane >> 4) * 4;
    float lv[2][4];
    #pragma unroll
    for (int mi = 0; mi < 2; mi++) {
        int ibase = i0 + wr + mi*16 + mrow;
        float4 l4 = *(const float4*)&linv[(size_t)h*768 + ibase];
        lv[mi][0] = l4.x; lv[mi][1] = l4.y; lv[mi][2] = l4.z; lv[mi][3] = l4.w;
    }
    if (nd0 < 128) {
        #pragma unroll
        for (int mi = 0; mi < 2; mi++) {
            #pragma unroll
            for (int ni = 0; ni < 2; ni++) {
                int d = nd0 + wc + ni*16 + fr;
                #pragma unroll
                for (int rr = 0; rr < 4; rr++) {
                    int i = i0 + wr + mi*16 + mrow + rr;
                    concat[(size_t)i*CONCAT + h*128 + d] = f2bf(acc[mi][ni][rr] * lv[mi][rr]);
                }
            }
        }
    } else {
        float* opt_s = (float*)&As[0][0];
        #pragma unroll
        for (int mi = 0; mi < 2; mi++) {
            #pragma unroll
            for (int ni = 0; ni < 2; ni++) {
                int c = wc + ni*16 + fr;
                if (c < 36) {
                    #pragma unroll
                    for (int rr = 0; rr < 4; rr++) {
                        int rl = wr + mi*16 + mrow + rr;
                        opt_s[rl*36 + c] = acc[mi][ni][rr] * lv[mi][rr];
                    }
                }
            }
        }
        __syncthreads();
        for (int it = tid; it < 768; it += 256) {
            int rl = it / 12, pp = it % 12;
            int i = i0 + rl;
            const float* R = rot + i*9;
            const float* T = trans + i*3;
            float y0 = opt_s[rl*36 + pp*3 + 0] - T[0];
            float y1 = opt_s[rl*36 + pp*3 + 1] - T[1];
            float y2 = opt_s[rl*36 + pp*3 + 2] - T[2];
            float o0 = R[0]*y0 + R[3]*y1 + R[6]*y2;
            float o1 = R[1]*y0 + R[4]*y1 + R[7]*y2;
            float o2 = R[2]*y0 + R[5]*y1 + R[8]*y2;
            float nrm = sqrtf(o0*o0 + o1*o1 + o2*o2 + 1e-8f);
            int hp = h*12 + pp;
            unsigned short* cb = concat + (size_t)i*CONCAT;
            cb[1024 +   0 + hp] = f2bf(o0);
            cb[1024 +  96 + hp] = f2bf(o1);
            cb[1024 + 192 + hp] = f2bf(o2);
            cb[1312 + hp] = f2bf(nrm);
        }
    }
}

// ---------------------------------------------------------------------------
// tail: LN1 + transition MLP (3 MFMA stages, Wt f32 inline cvt) + LN2 +
// upd + frame, row-local.
// ---------------------------------------------------------------------------
__global__ __launch_bounds__(256) void tail_kernel(
    const float* __restrict__ s, const float* __restrict__ ipa,
    const float* __restrict__ bo,
    const float* __restrict__ g1, const float* __restrict__ be1,
    const float* __restrict__ Wt1, const float* __restrict__ bt1,
    const float* __restrict__ Wt2, const float* __restrict__ bt2,
    const float* __restrict__ Wt3, const float* __restrict__ bt3,
    const float* __restrict__ g2, const float* __restrict__ be2,
    const float* __restrict__ Wbb, const float* __restrict__ bbb,
    const float* __restrict__ mask,
    const float* __restrict__ rot, const float* __restrict__ trans,
    float* __restrict__ out, float* __restrict__ rot_out, float* __restrict__ trans_out)
{
    __shared__ float s1f[32][257];
    __shared__ unsigned short Ab[32][264];
    __shared__ float upd_s[32][6];
    int i0 = blockIdx.x * 32;
    int tid = threadIdx.x, lane = tid & 63, wid = tid >> 6;
    int fr = lane & 15, fc = (lane >> 4) * 8, mrow = (lane >> 4) * 4;

    int r = tid >> 3, cg = (tid & 7) * 32;
    {
        float xv[32];
        float sum = 0.f, sq = 0.f;
        #pragma unroll
        for (int q = 0; q < 8; q++) {
            float4 a = *(const float4*)&s[(size_t)(i0 + r)*256 + cg + q*4];
            float4 b = *(const float4*)&ipa[(size_t)(i0 + r)*256 + cg + q*4];
            float4 c = *(const float4*)&bo[cg + q*4];
            float v0 = a.x + b.x + c.x, v1 = a.y + b.y + c.y;
            float v2 = a.z + b.z + c.z, v3 = a.w + b.w + c.w;
            xv[q*4+0] = v0; xv[q*4+1] = v1; xv[q*4+2] = v2; xv[q*4+3] = v3;
            sum += v0 + v1 + v2 + v3;
            sq  += v0*v0 + v1*v1 + v2*v2 + v3*v3;
        }
        #pragma unroll
        for (int d = 1; d < 8; d <<= 1) { sum += __shfl_xor(sum, d); sq += __shfl_xor(sq, d); }
        float mu = sum * (1.0f/256.0f);
        float var = sq * (1.0f/256.0f) - mu*mu;
        float rsig = 1.0f / sqrtf(var + 1e-5f);
        #pragma unroll
        for (int c = 0; c < 32; c++) {
            float o = (xv[c] - mu) * rsig * g1[cg + c] + be1[cg + c];
            s1f[r][cg + c] = o;
            Ab[r][cg + c] = f2bf(o);
        }
    }
    __syncthreads();

    const float* Ws[3] = {Wt1, Wt2, Wt3};
    const float* Bs[3] = {bt1, bt2, bt3};
    #pragma unroll
    for (int stage = 0; stage < 3; stage++) {
        const float* W = Ws[stage];
        const float* bias = Bs[stage];
        v4f acc[2][4] = {};
        #pragma unroll
        for (int k0 = 0; k0 < 8; k0++) {
            v8bf a0 = *(const v8bf*)&Ab[fr][k0*32 + fc];
            v8bf a1 = *(const v8bf*)&Ab[16 + fr][k0*32 + fc];
            #pragma unroll
            for (int n = 0; n < 4; n++) {
                int d = wid*64 + n*16 + fr;
                v8bf b = cvt8(&W[(size_t)d*256 + k0*32 + fc]);
                acc[0][n] = __builtin_amdgcn_mfma_f32_16x16x32_bf16(a0, b, acc[0][n], 0, 0, 0);
                acc[1][n] = __builtin_amdgcn_mfma_f32_16x16x32_bf16(a1, b, acc[1][n], 0, 0, 0);
            }
        }
        __syncthreads();
        if (stage < 2) {
            #pragma unroll
            for (int mi = 0; mi < 2; mi++) {
                #pragma unroll
                for (int n = 0; n < 4; n++) {
                    int d = wid*64 + n*16 + fr;
                    #pragma unroll
                    for (int rr = 0; rr < 4; rr++) {
                        int m = mi*16 + mrow + rr;
                        Ab[m][d] = f2bf(fmaxf(acc[mi][n][rr] + bias[d], 0.f));
                    }
                }
            }
        } else {
            #pragma unroll
            for (int mi = 0; mi < 2; mi++) {
                #pragma unroll
                for (int n = 0; n < 4; n++) {
                    int d = wid*64 + n*16 + fr;
                    #pragma unroll
                    for (int rr = 0; rr < 4; rr++) {
                        int m = mi*16 + mrow + rr;
                        s1f[m][d] += acc[mi][n][rr] + bias[d];
                    }
                }
            }
        }
        __syncthreads();
    }

    {
        float xv[32];
        float sum = 0.f, sq = 0.f;
        #pragma unroll
        for (int c = 0; c < 32; c++) {
            float v = s1f[r][cg + c];
            xv[c] = v; sum += v; sq += v*v;
        }
        #pragma unroll
        for (int d = 1; d < 8; d <<= 1) { sum += __shfl_xor(sum, d); sq += __shfl_xor(sq, d); }
        float mu = sum * (1.0f/256.0f);
        float var = sq * (1.0f/256.0f) - mu*mu;
        float rsig = 1.0f / sqrtf(var + 1e-5f);
        float o4[32];
        #pragma unroll
        for (int c = 0; c < 32; c++)
            o4[c] = (xv[c] - mu) * rsig * g2[cg + c] + be2[cg + c];
        #pragma unroll
        for (int q = 0; q < 8; q++) {
            float4 w; w.x = o4[q*4]; w.y = o4[q*4+1]; w.z = o4[q*4+2]; w.w = o4[q*4+3];
            *(float4*)&out[(size_t)(i0 + r)*256 + cg + q*4] = w;
        }
        __syncthreads();
        #pragma unroll
        for (int c = 0; c < 32; c++) s1f[r][cg + c] = o4[c];
    }
    __syncthreads();

    if (tid < 192) {
        int rr = tid / 6, d = tid % 6;
        float acc = bbb[d];
        const float* wb = Wbb + d*256;
        #pragma unroll 8
        for (int c = 0; c < 256; c++) acc += s1f[rr][c] * wb[c];
        upd_s[rr][d] = acc * mask[i0 + rr];
    }
    __syncthreads();

    if (tid < 32) {
        int i = i0 + tid;
        float u0 = upd_s[tid][0], u1 = upd_s[tid][1], u2 = upd_s[tid][2];
        float t0 = upd_s[tid][3], t1 = upd_s[tid][4], t2 = upd_s[tid][5];
        float n = sqrtf(1.f + u0*u0 + u1*u1 + u2*u2);
        float w = 1.f/n, x = u0/n, y = u1/n, z = u2/n;
        float R[3][3];
        R[0][0] = 1.f - 2.f*(y*y + z*z); R[0][1] = 2.f*(x*y - w*z);       R[0][2] = 2.f*(x*z + w*y);
        R[1][0] = 2.f*(x*y + w*z);       R[1][1] = 1.f - 2.f*(x*x + z*z); R[1][2] = 2.f*(y*z - w*x);
        R[2][0] = 2.f*(x*z - w*y);       R[2][1] = 2.f*(y*z + w*x);       R[2][2] = 1.f - 2.f*(x*x + y*y);
        const float* Ri = rot + i*9;
        #pragma unroll
        for (int a = 0; a < 3; a++) {
            #pragma unroll
            for (int b = 0; b < 3; b++) {
                float acc = 0.f;
                #pragma unroll
                for (int j = 0; j < 3; j++) acc += Ri[a*3+j]*R[j][b];
                rot_out[i*9 + a*3 + b] = acc;
            }
            trans_out[i*3 + a] = trans[i*3 + a] + Ri[a*3+0]*t0 + Ri[a*3+1]*t1 + Ri[a*3+2]*t2;
        }
    }
}

// ---------------------------------------------------------------------------
extern "C" void kernel_launch(void* const* d_in, const int* in_sizes, int n_in,
                              void* d_out, int out_size, void* d_ws, size_t ws_size,
                              hipStream_t stream)
{
    const float* s      = (const float*)d_in[0];
    const float* p      = (const float*)d_in[1];
    const float* rot    = (const float*)d_in[2];
    const float* trans  = (const float*)d_in[3];
    const float* mask   = (const float*)d_in[4];
    const float* Wq     = (const float*)d_in[5];
    const float* bq     = (const float*)d_in[6];
    const float* Wkv    = (const float*)d_in[7];
    const float* bkv    = (const float*)d_in[8];
    const float* Wqp    = (const float*)d_in[9];
    const float* bqp    = (const float*)d_in[10];
    const float* Wkvp   = (const float*)d_in[11];
    const float* bkvp   = (const float*)d_in[12];
    const float* Wpb    = (const float*)d_in[13];
    const float* bpb    = (const float*)d_in[14];
    const float* Wo     = (const float*)d_in[15];
    const float* bo     = (const float*)d_in[16];
    const float* Wt1    = (const float*)d_in[17];
    const float* bt1    = (const float*)d_in[18];
    const float* Wt2    = (const float*)d_in[19];
    const float* bt2    = (const float*)d_in[20];
    const float* Wt3    = (const float*)d_in[21];
    const float* bt3    = (const float*)d_in[22];
    const float* Wbb    = (const float*)d_in[23];
    const float* bbb    = (const float*)d_in[24];
    const float* head_w = (const float*)d_in[25];
    const float* g1     = (const float*)d_in[26];
    const float* be1    = (const float*)d_in[27];
    const float* g2     = (const float*)d_in[28];
    const float* be2    = (const float*)d_in[29];

    float* out = (float*)d_out;
    char*  wsb = (char*)d_ws;

    size_t off = 0;
    auto alloc = [&](size_t bytes) -> char* {
        char* ptr = wsb + off;
        off += (bytes + 255) & ~(size_t)255;
        return ptr;
    };
    float* qpraw   = (float*)alloc((size_t)NN*192*4);
    float* kvpraw  = (float*)alloc((size_t)NN*480*4);
    float* att     = (float*)alloc((size_t)8*768*768*4);
    float* ipa     = (float*)alloc((size_t)NN*256*4);
    float* linv    = (float*)alloc((size_t)8*768*4);
    float* lpart   = (float*)alloc((size_t)16*768*4);
    float* opart   = (float*)alloc((size_t)2*768*1024*4);
    unsigned* m0enc = (unsigned*)alloc((size_t)8*768*4);
    unsigned short* q_bf    = (unsigned short*)alloc((size_t)NN*1024*2);
    unsigned short* kv_bf   = (unsigned short*)alloc((size_t)NN*2048*2);
    unsigned short* qph     = (unsigned short*)alloc((size_t)NN*256*2);
    unsigned short* qpl     = (unsigned short*)alloc((size_t)NN*256*2);
    unsigned short* kph     = (unsigned short*)alloc((size_t)NN*256*2);
    unsigned short* kpl     = (unsigned short*)alloc((size_t)NN*256*2);
    unsigned short* Vc      = (unsigned short*)alloc((size_t)8*192*768*2);
    unsigned short* att_bf  = (unsigned short*)alloc((size_t)8*768*768*2);
    unsigned short* concat  = (unsigned short*)alloc((size_t)NN*CONCAT*2);

    // 0) zero-init atomic targets
    hipMemsetAsync(ipa, 0, (size_t)NN*256*4, stream);
    hipMemsetAsync(m0enc, 0, (size_t)8*768*4, stream);

    // 1) All projections in one GEMM launch (f32 inputs, inline cvt)
    ProjDesc pd;
    pd.W[0] = Wq;   pd.bias[0] = bq;   pd.dstb[0] = q_bf;   pd.dstf[0] = nullptr; pd.D[0] = 1024; pd.ldc[0] = 1024; pd.mode[0] = 2;
    pd.W[1] = Wkv;  pd.bias[1] = bkv;  pd.dstb[1] = kv_bf;  pd.dstf[1] = nullptr; pd.D[1] = 2048; pd.ldc[1] = 2048; pd.mode[1] = 2;
    pd.W[2] = Wqp;  pd.bias[2] = bqp;  pd.dstb[2] = nullptr; pd.dstf[2] = qpraw;  pd.D[2] = 192;  pd.ldc[2] = 192;  pd.mode[2] = 0;
    pd.W[3] = Wkvp; pd.bias[3] = bkvp; pd.dstb[3] = nullptr; pd.dstf[3] = kvpraw; pd.D[3] = 480;  pd.ldc[3] = 480;  pd.mode[3] = 0;
    pd.blk_start[0] = 0; pd.blk_start[1] = 16; pd.blk_start[2] = 48; pd.blk_start[3] = 51; pd.blk_start[4] = 59;
    proj_all<<<dim3(59, 12), 256, 0, stream>>>(s, pd);

    // 2) rotate + vtrans merged
    prep2_kernel<<<672 + 192, 256, 0, stream>>>(
        qpraw, kvpraw, rot, trans, kv_bf, qph, qpl, kph, kpl, Vc);

    // 3) logits (+row max via atomicMax)
    logits_mfma<<<dim3(12, 12, 8), 256, 0, stream>>>(
        q_bf, kv_bf, qph, qpl, kph, kpl, mask, head_w, att, m0enc);

    // 4) single-pass p kernel, split over 2 j-halves
    fused_p3s_kernel<<<dim3(768, 2), 256, 0, stream>>>(
        att, p, Wpb, bpb, m0enc, att_bf, lpart, opart);
    preduce_kernel<<<768, 256, 0, stream>>>(lpart, opart, linv, concat);

    // 5) o / opt (+final epilogue)
    attvc_mfma<<<dim3(3, 12, 8), 256, 0, stream>>>(att_bf, Vc, linv, rot, trans, concat);

    // 6) Output projection (split-K into zeroed ipa, Wo f32 inline cvt)
    wo_gemm<<<dim3(4,12,4), 256, 0, stream>>>(concat, Wo, ipa);

    // 7) fused tail: LN1 + MLP + LN2 + upd + frame (Wt f32 inline cvt)
    tail_kernel<<<24, 256, 0, stream>>>(
        s, ipa, bo, g1, be1, Wt1, bt1, Wt2, bt2, Wt3, bt3,
        g2, be2, Wbb, bbb, mask, rot, trans,
        out, out + (size_t)NN*256, out + (size_t)NN*256 + (size_t)NN*9);
}

// Round 11
// 186.484 us; speedup vs baseline: 1.0520x; 1.0520x over previous
//
#include <hip/hip_runtime.h>
#include <hip/hip_bf16.h>
#include <math.h>

// Problem constants
#define NN 768
#define CS 256
#define CZ 128
#define CH 128
#define HH 8
#define PQK 8
#define PV 12
#define CONCAT 2432   // 1024 + 288 + 96 + 1024
#define ATT_HSTRIDE (768*768)

typedef __bf16 v8bf __attribute__((ext_vector_type(8)));
typedef __bf16 v4bf __attribute__((ext_vector_type(4)));
typedef float  v4f  __attribute__((ext_vector_type(4)));

__device__ inline unsigned short f2bf(float f) {
    union { float f; unsigned u; } v; v.f = f;
    unsigned r = v.u + 0x7FFFu + ((v.u >> 16) & 1u);
    return (unsigned short)(r >> 16);
}
__device__ inline float bf2f(unsigned short u) {
    union { unsigned u; float f; } v; v.u = ((unsigned)u) << 16; return v.f;
}
// order-preserving float<->uint encoding (for atomicMax on floats)
__device__ inline unsigned encf(float f) {
    unsigned u = __float_as_uint(f);
    return (u >> 31) ? ~u : (u | 0x80000000u);
}
__device__ inline float decf(unsigned e) {
    unsigned u = (e >> 31) ? (e & 0x7FFFFFFFu) : ~e;
    return __uint_as_float(u);
}

// ---------------------------------------------------------------------------
// Batched f32 -> bf16 conversion
// ---------------------------------------------------------------------------
#define NCVT 9
struct CvtDesc {
    const float* src[NCVT];
    unsigned short* dst[NCVT];
    int nelem[NCVT];
    int blk_start[NCVT + 1];
};

__global__ __launch_bounds__(256) void cvt_many(CvtDesc d)
{
    int b = blockIdx.x;
    int seg = 0;
    #pragma unroll
    for (int i = 0; i < NCVT - 1; i++) if (b >= d.blk_start[i + 1]) seg = i + 1;
    int local = b - d.blk_start[seg];
    int base = local * 2048 + threadIdx.x;
    const float* s = d.src[seg];
    unsigned short* o = d.dst[seg];
    int n = d.nelem[seg];
    #pragma unroll
    for (int r = 0; r < 8; r++) {
        int idx = base + r * 256;
        if (idx < n) o[idx] = f2bf(s[idx]);
    }
}

// ---------------------------------------------------------------------------
// Combined projection GEMM: 4 weight segments, shared A = s_bf, K=256.
// ---------------------------------------------------------------------------
struct ProjDesc {
    const unsigned short* W[4];
    const float* bias[4];
    unsigned short* dstb[4];
    float* dstf[4];
    int D[4];
    int ldc[4];
    int mode[4];
    int blk_start[5];
};

__global__ __launch_bounds__(256) void proj_all(const unsigned short* __restrict__ A, ProjDesc d)
{
    __shared__ unsigned short As[64][40];
    __shared__ unsigned short Ws[64][40];
    int bx = blockIdx.x;
    int seg = 0;
    #pragma unroll
    for (int q = 0; q < 3; q++) if (bx >= d.blk_start[q + 1]) seg = q + 1;
    int bd = (bx - d.blk_start[seg]) * 64;
    int bi = blockIdx.y * 64;
    const unsigned short* W = d.W[seg];
    int D = d.D[seg], ldc = d.ldc[seg];

    int tid = threadIdx.x, lane = tid & 63, wid = tid >> 6;
    int wr = (wid >> 1) * 32, wc = (wid & 1) * 32;
    v4f acc[2][2] = {};
    int lrow = tid >> 2, lcol = (tid & 3) * 8;
    const unsigned short* Ap = A + (size_t)(bi + lrow) * 256 + lcol;
    const unsigned short* Wp = W + (size_t)(bd + lrow) * 256 + lcol;
    bool wv = (bd + lrow) < D;
    int fr = lane & 15, fc = (lane >> 4) * 8;

    for (int k0 = 0; k0 < 256; k0 += 32) {
        *(int4*)&As[lrow][lcol] = *(const int4*)(Ap + k0);
        int4 wz = {0, 0, 0, 0};
        *(int4*)&Ws[lrow][lcol] = wv ? *(const int4*)(Wp + k0) : wz;
        __syncthreads();
        v8bf a0 = *(const v8bf*)&As[wr + fr][fc];
        v8bf a1 = *(const v8bf*)&As[wr + 16 + fr][fc];
        v8bf b0 = *(const v8bf*)&Ws[wc + fr][fc];
        v8bf b1 = *(const v8bf*)&Ws[wc + 16 + fr][fc];
        acc[0][0] = __builtin_amdgcn_mfma_f32_16x16x32_bf16(a0, b0, acc[0][0], 0, 0, 0);
        acc[0][1] = __builtin_amdgcn_mfma_f32_16x16x32_bf16(a0, b1, acc[0][1], 0, 0, 0);
        acc[1][0] = __builtin_amdgcn_mfma_f32_16x16x32_bf16(a1, b0, acc[1][0], 0, 0, 0);
        acc[1][1] = __builtin_amdgcn_mfma_f32_16x16x32_bf16(a1, b1, acc[1][1], 0, 0, 0);
        __syncthreads();
    }
    const float* bias = d.bias[seg];
    int mode = d.mode[seg];
    unsigned short* Cb = d.dstb[seg];
    float* Cf = d.dstf[seg];
    int mrow = (lane >> 4) * 4;
    #pragma unroll
    for (int mi = 0; mi < 2; mi++) {
        #pragma unroll
        for (int ni = 0; ni < 2; ni++) {
            int dd = bd + wc + ni * 16 + fr;
            if (dd < D) {
                #pragma unroll
                for (int r = 0; r < 4; r++) {
                    int m = bi + wr + mi * 16 + mrow + r;
                    float v = acc[mi][ni][r] + bias[dd];
                    if (mode == 2) Cb[(size_t)m * ldc + dd] = f2bf(v);
                    else           Cf[(size_t)m * ldc + dd] = v;
                }
            }
        }
    }
}

// ---------------------------------------------------------------------------
// Generic MFMA bf16 GEMM (used for Wo split-K)
// ---------------------------------------------------------------------------
template<int SPLITK, int MODE, int RELU>
__global__ __launch_bounds__(256) void mfma_gemm(
    const unsigned short* __restrict__ A,
    const unsigned short* __restrict__ W,
    const float* __restrict__ bias,
    float* __restrict__ C,
    unsigned short* __restrict__ Cb,
    int D, int K, int ldc)
{
    __shared__ unsigned short As[64][40];
    __shared__ unsigned short Ws[64][40];
    int tid = threadIdx.x;
    int bi = blockIdx.y * 64;
    int bd = blockIdx.x * 64;
    int kpb = K / SPLITK;
    int k0b = blockIdx.z * kpb;
    int lane = tid & 63;
    int wid = tid >> 6;
    int wr = (wid >> 1) * 32, wc = (wid & 1) * 32;
    v4f acc[2][2] = {};
    int lrow = tid >> 2;
    int lcol = (tid & 3) * 8;
    const unsigned short* Ap = A + (size_t)(bi + lrow) * K + lcol;
    const unsigned short* Wp = W + (size_t)(bd + lrow) * K + lcol;
    bool wv = (bd + lrow) < D;
    int fr = lane & 15, fc = (lane >> 4) * 8;

    for (int k0 = k0b; k0 < k0b + kpb; k0 += 32) {
        *(int4*)&As[lrow][lcol] = *(const int4*)(Ap + k0);
        int4 wz = {0, 0, 0, 0};
        *(int4*)&Ws[lrow][lcol] = wv ? *(const int4*)(Wp + k0) : wz;
        __syncthreads();
        v8bf a0 = *(const v8bf*)&As[wr + fr][fc];
        v8bf a1 = *(const v8bf*)&As[wr + 16 + fr][fc];
        v8bf b0 = *(const v8bf*)&Ws[wc + fr][fc];
        v8bf b1 = *(const v8bf*)&Ws[wc + 16 + fr][fc];
        acc[0][0] = __builtin_amdgcn_mfma_f32_16x16x32_bf16(a0, b0, acc[0][0], 0, 0, 0);
        acc[0][1] = __builtin_amdgcn_mfma_f32_16x16x32_bf16(a0, b1, acc[0][1], 0, 0, 0);
        acc[1][0] = __builtin_amdgcn_mfma_f32_16x16x32_bf16(a1, b0, acc[1][0], 0, 0, 0);
        acc[1][1] = __builtin_amdgcn_mfma_f32_16x16x32_bf16(a1, b1, acc[1][1], 0, 0, 0);
        __syncthreads();
    }
    int mrow = (lane >> 4) * 4;
    #pragma unroll
    for (int mi = 0; mi < 2; mi++) {
        #pragma unroll
        for (int ni = 0; ni < 2; ni++) {
            int d = bd + wc + ni * 16 + fr;
            if (d < D) {
                #pragma unroll
                for (int r = 0; r < 4; r++) {
                    int m = bi + wr + mi * 16 + mrow + r;
                    float v = acc[mi][ni][r];
                    if (SPLITK > 1) {
                        atomicAdd(&C[(size_t)m * ldc + d], v);
                    } else {
                        v += bias[d];
                        if (RELU) v = fmaxf(v, 0.f);
                        if (MODE != 2) C[(size_t)m * ldc + d] = v;
                        if (MODE >= 1) Cb[(size_t)m * ldc + d] = f2bf(v);
                    }
                }
            }
        }
    }
}

// ---------------------------------------------------------------------------
// prep2: rotate points (blocks < 672) + V transpose (blocks >= 672)
// ---------------------------------------------------------------------------
__global__ __launch_bounds__(256) void prep2_kernel(
    const float* __restrict__ qpraw, const float* __restrict__ kvpraw,
    const float* __restrict__ rot, const float* __restrict__ trans,
    const unsigned short* __restrict__ kv_bf,
    unsigned short* __restrict__ qph, unsigned short* __restrict__ qpl,
    unsigned short* __restrict__ kph, unsigned short* __restrict__ kpl,
    unsigned short* __restrict__ Vc)
{
    __shared__ unsigned short tile[32][136];
    int bx = blockIdx.x;
    int t = threadIdx.x;
    if (bx < 672) {
        int id = bx*256 + t;
        int i = id / (HH*28);
        int rem = id % (HH*28);
        int h = rem / 28;
        int idx = rem % 28;
        const float* R = rot + i*9;
        const float* T = trans + i*3;
        float s0, s1, s2;
        if (idx < 8) {
            s0 = qpraw[i*192 +   0 + h*8 + idx];
            s1 = qpraw[i*192 +  64 + h*8 + idx];
            s2 = qpraw[i*192 + 128 + h*8 + idx];
        } else {
            int pp = idx - 8;
            s0 = kvpraw[i*480 +   0 + h*20 + pp];
            s1 = kvpraw[i*480 + 160 + h*20 + pp];
            s2 = kvpraw[i*480 + 320 + h*20 + pp];
        }
        float ov[3];
        ov[0] = R[0]*s0 + R[1]*s1 + R[2]*s2 + T[0];
        ov[1] = R[3]*s0 + R[4]*s1 + R[5]*s2 + T[1];
        ov[2] = R[6]*s0 + R[7]*s1 + R[8]*s2 + T[2];
        if (idx < 8) {
            #pragma unroll
            for (int x = 0; x < 3; x++) {
                unsigned short hi = f2bf(ov[x]);
                qph[i*256 + h*32 + idx*3 + x] = hi;
                qpl[i*256 + h*32 + idx*3 + x] = f2bf(ov[x] - bf2f(hi));
            }
            if (idx == 0) {
                #pragma unroll
                for (int m = 24; m < 32; m++) { qph[i*256+h*32+m] = 0; qpl[i*256+h*32+m] = 0; }
            }
        } else if (idx < 16) {
            int pp = idx - 8;
            #pragma unroll
            for (int x = 0; x < 3; x++) {
                unsigned short hi = f2bf(ov[x]);
                kph[i*256 + h*32 + pp*3 + x] = hi;
                kpl[i*256 + h*32 + pp*3 + x] = f2bf(ov[x] - bf2f(hi));
            }
            if (idx == 8) {
                #pragma unroll
                for (int m = 24; m < 32; m++) { kph[i*256+h*32+m] = 0; kpl[i*256+h*32+m] = 0; }
            }
        } else {
            int ppv = idx - 16;
            #pragma unroll
            for (int x = 0; x < 3; x++)
                Vc[((size_t)h*192 + 128 + ppv*3 + x)*768 + i] = f2bf(ov[x]);
        }
    } else {
        int bx2 = bx - 672;
        int h = bx2 & 7, jt = bx2 >> 3;
        int r = t >> 3, c0 = (t & 7) * 16;
        const unsigned short* src = kv_bf + (size_t)(jt*32 + r)*2048 + h*256 + 128 + c0;
        *(int4*)&tile[r][c0]     = *(const int4*)src;
        *(int4*)&tile[r][c0 + 8] = *(const int4*)(src + 8);
        __syncthreads();
        int c = t >> 1, jh = (t & 1) * 16;
        unsigned short tmp[16];
        #pragma unroll
        for (int k = 0; k < 16; k++) tmp[k] = tile[jh + k][c];
        unsigned short* dst = Vc + ((size_t)h*192 + c)*768 + jt*32 + jh;
        *(int4*)dst       = *(int4*)&tmp[0];
        *(int4*)(dst + 8) = *(int4*)&tmp[8];
    }
}

// ---------------------------------------------------------------------------
// Logits via MFMA. Point fragments loaded DIRECT from global (L2-resident),
// Qss/Kss computed in-register (shfl reduce). LDS = Qs+Ks+mask only
// (~36 KB -> 4 blocks/CU). Row max folded in via order-encoded atomicMax.
// ---------------------------------------------------------------------------
__global__ __launch_bounds__(256) void logits_mfma(
    const unsigned short* __restrict__ q_bf, const unsigned short* __restrict__ kv_bf,
    const unsigned short* __restrict__ qph, const unsigned short* __restrict__ qpl,
    const unsigned short* __restrict__ kph, const unsigned short* __restrict__ kpl,
    const float* __restrict__ mask, const float* __restrict__ head_w,
    float* __restrict__ att, unsigned* __restrict__ m0enc)
{
    __shared__ unsigned short Qs[64][136];
    __shared__ unsigned short Ks[64][136];
    __shared__ float Mi[64], Mj[64];
    int h = blockIdx.z;
    int i0 = blockIdx.y * 64, j0 = blockIdx.x * 64;
    int tid = threadIdx.x, lane = tid & 63, wid = tid >> 6;
    int wr = (wid >> 1) * 32, wc = (wid & 1) * 32;
    int r = tid >> 2, cq = (tid & 3) * 32;
    const unsigned short* qg = q_bf  + (size_t)(i0 + r)*1024 + h*128 + cq;
    const unsigned short* kg = kv_bf + (size_t)(j0 + r)*2048 + h*256 + cq;
    #pragma unroll
    for (int kk = 0; kk < 4; kk++) {
        *(int4*)&Qs[r][cq + kk*8] = *(const int4*)(qg + kk*8);
        *(int4*)&Ks[r][cq + kk*8] = *(const int4*)(kg + kk*8);
    }
    if (tid < 64) {
        Mi[tid] = mask[i0 + tid];
        Mj[tid] = mask[j0 + tid];
    }
    int fr = lane & 15, fc = (lane >> 4) * 8;
    // direct point-fragment loads (rows 64B-aligned; m=24..31 zeroed in prep2)
    v8bf ah0 = *(const v8bf*)&qph[(size_t)(i0 + wr + fr)*256 + h*32 + fc];
    v8bf ah1 = *(const v8bf*)&qph[(size_t)(i0 + wr + 16 + fr)*256 + h*32 + fc];
    v8bf al0 = *(const v8bf*)&qpl[(size_t)(i0 + wr + fr)*256 + h*32 + fc];
    v8bf al1 = *(const v8bf*)&qpl[(size_t)(i0 + wr + 16 + fr)*256 + h*32 + fc];
    v8bf bh0 = *(const v8bf*)&kph[(size_t)(j0 + wc + fr)*256 + h*32 + fc];
    v8bf bh1 = *(const v8bf*)&kph[(size_t)(j0 + wc + 16 + fr)*256 + h*32 + fc];
    v8bf bl0 = *(const v8bf*)&kpl[(size_t)(j0 + wc + fr)*256 + h*32 + fc];
    v8bf bl1 = *(const v8bf*)&kpl[(size_t)(j0 + wc + 16 + fr)*256 + h*32 + fc];
    // in-register point norms: row wr+fr (q2a), wr+16+fr (q2b); cols likewise
    float q2a = 0.f, q2b = 0.f, k2a = 0.f, k2b = 0.f;
    #pragma unroll
    for (int m = 0; m < 8; m++) {
        float va = (float)ah0[m] + (float)al0[m];
        float vb = (float)ah1[m] + (float)al1[m];
        float wa = (float)bh0[m] + (float)bl0[m];
        float wb = (float)bh1[m] + (float)bl1[m];
        q2a += va*va; q2b += vb*vb; k2a += wa*wa; k2b += wb*wb;
    }
    q2a += __shfl_xor(q2a, 16); q2a += __shfl_xor(q2a, 32);
    q2b += __shfl_xor(q2b, 16); q2b += __shfl_xor(q2b, 32);
    k2a += __shfl_xor(k2a, 16); k2a += __shfl_xor(k2a, 32);
    k2b += __shfl_xor(k2b, 16); k2b += __shfl_xor(k2b, 32);

    v4f ap[2][2] = {};
    ap[0][0] = __builtin_amdgcn_mfma_f32_16x16x32_bf16(ah0, bh0, ap[0][0], 0, 0, 0);
    ap[0][1] = __builtin_amdgcn_mfma_f32_16x16x32_bf16(ah0, bh1, ap[0][1], 0, 0, 0);
    ap[1][0] = __builtin_amdgcn_mfma_f32_16x16x32_bf16(ah1, bh0, ap[1][0], 0, 0, 0);
    ap[1][1] = __builtin_amdgcn_mfma_f32_16x16x32_bf16(ah1, bh1, ap[1][1], 0, 0, 0);
    ap[0][0] = __builtin_amdgcn_mfma_f32_16x16x32_bf16(ah0, bl0, ap[0][0], 0, 0, 0);
    ap[0][1] = __builtin_amdgcn_mfma_f32_16x16x32_bf16(ah0, bl1, ap[0][1], 0, 0, 0);
    ap[1][0] = __builtin_amdgcn_mfma_f32_16x16x32_bf16(ah1, bl0, ap[1][0], 0, 0, 0);
    ap[1][1] = __builtin_amdgcn_mfma_f32_16x16x32_bf16(ah1, bl1, ap[1][1], 0, 0, 0);
    ap[0][0] = __builtin_amdgcn_mfma_f32_16x16x32_bf16(al0, bh0, ap[0][0], 0, 0, 0);
    ap[0][1] = __builtin_amdgcn_mfma_f32_16x16x32_bf16(al0, bh1, ap[0][1], 0, 0, 0);
    ap[1][0] = __builtin_amdgcn_mfma_f32_16x16x32_bf16(al1, bh0, ap[1][0], 0, 0, 0);
    ap[1][1] = __builtin_amdgcn_mfma_f32_16x16x32_bf16(al1, bh1, ap[1][1], 0, 0, 0);

    __syncthreads();   // Qs/Ks staged
    v4f aqk[2][2] = {};
    #pragma unroll
    for (int ks = 0; ks < 4; ks++) {
        v8bf a0 = *(const v8bf*)&Qs[wr + fr][ks*32 + fc];
        v8bf a1 = *(const v8bf*)&Qs[wr + 16 + fr][ks*32 + fc];
        v8bf b0 = *(const v8bf*)&Ks[wc + fr][ks*32 + fc];
        v8bf b1 = *(const v8bf*)&Ks[wc + 16 + fr][ks*32 + fc];
        aqk[0][0] = __builtin_amdgcn_mfma_f32_16x16x32_bf16(a0, b0, aqk[0][0], 0, 0, 0);
        aqk[0][1] = __builtin_amdgcn_mfma_f32_16x16x32_bf16(a0, b1, aqk[0][1], 0, 0, 0);
        aqk[1][0] = __builtin_amdgcn_mfma_f32_16x16x32_bf16(a1, b0, aqk[1][0], 0, 0, 0);
        aqk[1][1] = __builtin_amdgcn_mfma_f32_16x16x32_bf16(a1, b1, aqk[1][1], 0, 0, 0);
    }
    float hx = head_w[h];
    float sp = (hx > 20.f) ? hx : log1pf(__expf(hx));
    float hw = sp * 0.09622504486493764f;
    const float scale_qk = 0.05103103630798288f;
    int mrow = (lane >> 4) * 4;
    float val[2][2][4];
    #pragma unroll
    for (int mi = 0; mi < 2; mi++) {
        #pragma unroll
        for (int rr = 0; rr < 4; rr++) {
            float qss = __shfl((mi == 0) ? q2a : q2b, mrow + rr);
            #pragma unroll
            for (int ni = 0; ni < 2; ni++) {
                int jl = wc + ni*16 + fr;
                int il = wr + mi*16 + mrow + rr;
                float kss = (ni == 0) ? k2a : k2b;
                float v = aqk[mi][ni][rr]*scale_qk + hw*ap[mi][ni][rr]
                        - 0.5f*hw*(qss + kss)
                        + 100000.0f*(Mi[il]*Mj[jl] - 1.0f);
                val[mi][ni][rr] = v;
                att[(size_t)h*ATT_HSTRIDE + (size_t)(i0 + il)*768 + (j0 + jl)] = v;
            }
        }
    }
    // per-row max over this block's 64 j, then atomicMax into m0enc
    #pragma unroll
    for (int mi = 0; mi < 2; mi++) {
        #pragma unroll
        for (int rr = 0; rr < 4; rr++) {
            float m = fmaxf(val[mi][0][rr], val[mi][1][rr]);
            #pragma unroll
            for (int d2 = 1; d2 < 16; d2 <<= 1) m = fmaxf(m, __shfl_xor(m, d2));
            if (fr == 0) {
                int il = wr + mi*16 + mrow + rr;
                atomicMax(&m0enc[h*768 + i0 + il], encf(m));
            }
        }
    }
}

// ---------------------------------------------------------------------------
// fused_p3s: half of the j-range per block; single pass over p; MFMA bias +
// MFMA opair (B-fragments from ptile columns). Double-buffered ptile ->
// 2 barriers/tile with stage/compute overlap.
// ---------------------------------------------------------------------------
__global__ __launch_bounds__(256) void fused_p3s_kernel(
    const float* __restrict__ att0,
    const float* __restrict__ p,
    const float* __restrict__ Wpb, const float* __restrict__ bpb,
    const unsigned* __restrict__ m0enc,
    unsigned short* __restrict__ att_bf,
    float* __restrict__ lpart,
    float* __restrict__ opart)
{
    __shared__ unsigned short ptile[2][64][132];
    __shared__ unsigned short wt[16][72];
    __shared__ float bpb_s[8], m8[8], lsum_w[4][8];

    int i = blockIdx.x;
    int half = blockIdx.y;
    int jbase = half * 384;
    int tid = threadIdx.x, lane = tid & 63, wid = tid >> 6;
    int fr = lane & 15, fc = (lane >> 4) * 8;
    int mrow = (lane >> 4) * 4;

    for (int idx = tid; idx < 16*72; idx += 256) ((unsigned short*)wt)[idx] = 0;
    if (tid < 8) {
        bpb_s[tid] = bpb[tid];
        m8[tid] = decf(m0enc[tid*768 + i]);
    }

    v8bf aW[4];
    #pragma unroll
    for (int ks = 0; ks < 4; ks++) {
        v8bf v = {};
        if (fr < 8) {
            const float* wp = Wpb + fr*128 + ks*32 + fc;
            float4 w0 = *(const float4*)wp;
            float4 w1 = *(const float4*)(wp + 4);
            v[0] = (__bf16)w0.x; v[1] = (__bf16)w0.y; v[2] = (__bf16)w0.z; v[3] = (__bf16)w0.w;
            v[4] = (__bf16)w1.x; v[5] = (__bf16)w1.y; v[6] = (__bf16)w1.z; v[7] = (__bf16)w1.w;
        }
        aW[ks] = v;
    }

    const float* pbase = p + (size_t)i*98304 + (size_t)jbase*128;
    int ldrow = tid >> 4, ldz = (tid & 15) * 8;   // each thread: rows ldrow+16k
    float4 pfA[4], pfB[4];
    // load tile 0 -> regs, stage -> buf0, load tile 1 -> regs
    #pragma unroll
    for (int r2 = 0; r2 < 4; r2++) {
        const float* src = pbase + (size_t)(r2*16 + ldrow)*128 + ldz;
        pfA[r2] = *(const float4*)src;
        pfB[r2] = *(const float4*)(src + 4);
    }
    #pragma unroll
    for (int r2 = 0; r2 < 4; r2++) {
        v4bf lo, hi;
        lo[0] = (__bf16)pfA[r2].x; lo[1] = (__bf16)pfA[r2].y;
        lo[2] = (__bf16)pfA[r2].z; lo[3] = (__bf16)pfA[r2].w;
        hi[0] = (__bf16)pfB[r2].x; hi[1] = (__bf16)pfB[r2].y;
        hi[2] = (__bf16)pfB[r2].z; hi[3] = (__bf16)pfB[r2].w;
        *(v4bf*)&ptile[0][r2*16 + ldrow][ldz]     = lo;
        *(v4bf*)&ptile[0][r2*16 + ldrow][ldz + 4] = hi;
    }
    #pragma unroll
    for (int r2 = 0; r2 < 4; r2++) {
        const float* src = pbase + (size_t)(64 + r2*16 + ldrow)*128 + ldz;
        pfA[r2] = *(const float4*)src;
        pfB[r2] = *(const float4*)(src + 4);
    }
    __syncthreads();
    float m0l[4];
    #pragma unroll
    for (int r2 = 0; r2 < 4; r2++) m0l[r2] = (mrow == 0) ? m8[r2] : m8[4 + r2];

    v4f accD[2] = {};
    float lacc[4] = {0.f, 0.f, 0.f, 0.f};
    const float sqrt13 = 0.57735026918962576f;
    bool expo = (mrow < 8);

    for (int t64 = 0; t64 < 6; t64++) {
        int cur = t64 & 1;
        int j0 = jbase + t64 * 64;

        // bias mfma on ptile[cur]
        v4f bd = {};
        #pragma unroll
        for (int ks = 0; ks < 4; ks++) {
            int c = ks*32 + fc;
            v4bf blo = *(const v4bf*)&ptile[cur][16*wid + fr][c];
            v4bf bhi = *(const v4bf*)&ptile[cur][16*wid + fr][c + 4];
            v8bf b;
            b[0]=blo[0]; b[1]=blo[1]; b[2]=blo[2]; b[3]=blo[3];
            b[4]=bhi[0]; b[5]=bhi[1]; b[6]=bhi[2]; b[7]=bhi[3];
            bd = __builtin_amdgcn_mfma_f32_16x16x32_bf16(aW[ks], b, bd, 0, 0, 0);
        }
        // exp + wt + att_bf + row-sum
        if (expo) {
            int j = 16*wid + fr;
            float a0v[4], w8[4];
            #pragma unroll
            for (int r2 = 0; r2 < 4; r2++)
                a0v[r2] = att0[((size_t)(mrow + r2)*768 + i)*768 + j0 + j];
            #pragma unroll
            for (int r2 = 0; r2 < 4; r2++) {
                int h = mrow + r2;
                float L = a0v[r2] + sqrt13*(bd[r2] + bpb_s[h]);
                w8[r2] = __expf(fminf(L - m0l[r2], 60.f));
            }
            #pragma unroll
            for (int r2 = 0; r2 < 4; r2++) {
                int h = mrow + r2;
                unsigned short wb = f2bf(w8[r2]);
                wt[h][j] = wb;
                att_bf[((size_t)h*768 + i)*768 + j0 + j] = wb;
            }
            #pragma unroll
            for (int m = 1; m < 16; m <<= 1) {
                #pragma unroll
                for (int r2 = 0; r2 < 4; r2++) w8[r2] += __shfl_xor(w8[r2], m);
            }
            #pragma unroll
            for (int r2 = 0; r2 < 4; r2++) lacc[r2] += w8[r2];
        }
        // stage regs (tile t64+1) -> other buffer; issue loads for t64+2
        if (t64 < 5) {
            #pragma unroll
            for (int r2 = 0; r2 < 4; r2++) {
                v4bf lo, hi;
                lo[0] = (__bf16)pfA[r2].x; lo[1] = (__bf16)pfA[r2].y;
                lo[2] = (__bf16)pfA[r2].z; lo[3] = (__bf16)pfA[r2].w;
                hi[0] = (__bf16)pfB[r2].x; hi[1] = (__bf16)pfB[r2].y;
                hi[2] = (__bf16)pfB[r2].z; hi[3] = (__bf16)pfB[r2].w;
                *(v4bf*)&ptile[cur ^ 1][r2*16 + ldrow][ldz]     = lo;
                *(v4bf*)&ptile[cur ^ 1][r2*16 + ldrow][ldz + 4] = hi;
            }
            if (t64 < 4) {
                #pragma unroll
                for (int r2 = 0; r2 < 4; r2++) {
                    const float* src = pbase + (size_t)((t64+2)*64 + r2*16 + ldrow)*128 + ldz;
                    pfA[r2] = *(const float4*)src;
                    pfB[r2] = *(const float4*)(src + 4);
                }
            }
        }
        __syncthreads();   // wt visible; next buffer staged

        // opair mfma: D[h][z], A = wt rows, B = ptile[cur] columns
        #pragma unroll
        for (int mm = 0; mm < 2; mm++) {
            int zcol = (2*wid + mm)*16 + fr;
            #pragma unroll
            for (int ks = 0; ks < 2; ks++) {
                v8bf b;
                #pragma unroll
                for (int kk = 0; kk < 8; kk++)
                    b[kk] = *(const __bf16*)&ptile[cur][ks*32 + fc + kk][zcol];
                v8bf a = *(const v8bf*)&wt[fr][ks*32 + fc];
                accD[mm] = __builtin_amdgcn_mfma_f32_16x16x32_bf16(a, b, accD[mm], 0, 0, 0);
            }
        }
        __syncthreads();   // protect wt + ptile[cur] for next iteration
    }

    if (fr == 0 && expo) {
        #pragma unroll
        for (int r2 = 0; r2 < 4; r2++) lsum_w[wid][mrow + r2] = lacc[r2];
    }
    __syncthreads();
    if (tid < 8) {
        lpart[(size_t)(half*8 + tid)*768 + i] =
            lsum_w[0][tid] + lsum_w[1][tid] + lsum_w[2][tid] + lsum_w[3][tid];
    }
    if (expo) {
        float* ob = opart + (size_t)(half*768 + i)*1024;
        #pragma unroll
        for (int mm = 0; mm < 2; mm++) {
            int z = (2*wid + mm)*16 + fr;
            #pragma unroll
            for (int r2 = 0; r2 < 4; r2++)
                ob[(mrow + r2)*128 + z] = accD[mm][r2];
        }
    }
}

// ---------------------------------------------------------------------------
// preduce: sum the two j-half partials -> linv + opair into concat
// ---------------------------------------------------------------------------
__global__ __launch_bounds__(256) void preduce_kernel(
    const float* __restrict__ lpart, const float* __restrict__ opart,
    float* __restrict__ linv, unsigned short* __restrict__ concat)
{
    __shared__ float inv_s[8];
    int i = blockIdx.x, t = threadIdx.x;
    if (t < 8) {
        float l = lpart[(size_t)t*768 + i] + lpart[(size_t)(8 + t)*768 + i];
        float iv = 1.0f / l;
        inv_s[t] = iv;
        linv[(size_t)t*768 + i] = iv;
    }
    __syncthreads();
    const float* o0 = opart + (size_t)i*1024;
    const float* o1 = opart + (size_t)(768 + i)*1024;
    #pragma unroll
    for (int k = 0; k < 4; k++) {
        int c = t + k*256;
        float s = o0[c] + o1[c];
        concat[(size_t)i*CONCAT + 1408 + c] = f2bf(s * inv_s[c >> 7]);
    }
}

// ---------------------------------------------------------------------------
// Fused (o | opt) = (att_unnorm @ Vc^T) * linv per h; opt blocks also do
// rot^T/trans/norm epilogue.
// ---------------------------------------------------------------------------
__global__ __launch_bounds__(256) void attvc_mfma(
    const unsigned short* __restrict__ att_bf, const unsigned short* __restrict__ Vc,
    const float* __restrict__ linv, const float* __restrict__ rot,
    const float* __restrict__ trans, unsigned short* __restrict__ concat)
{
    __shared__ unsigned short As[64][72];
    __shared__ unsigned short Bs[64][72];
    int h = blockIdx.z;
    int i0 = blockIdx.y * 64, nd0 = blockIdx.x * 64;
    int tid = threadIdx.x, lane = tid & 63, wid = tid >> 6;
    int wr = (wid >> 1) * 32, wc = (wid & 1) * 32;
    int r = tid >> 2, c8 = (tid & 3) * 16;
    int fr = lane & 15, fc = (lane >> 4) * 8;
    v4f acc[2][2] = {};
    for (int k0 = 0; k0 < 768; k0 += 64) {
        const unsigned short* ag = att_bf + ((size_t)h*768 + i0 + r)*768 + k0 + c8;
        const unsigned short* bg = Vc + ((size_t)h*192 + nd0 + r)*768 + k0 + c8;
        *(int4*)&As[r][c8]     = *(const int4*)ag;
        *(int4*)&As[r][c8 + 8] = *(const int4*)(ag + 8);
        *(int4*)&Bs[r][c8]     = *(const int4*)bg;
        *(int4*)&Bs[r][c8 + 8] = *(const int4*)(bg + 8);
        __syncthreads();
        #pragma unroll
        for (int ks = 0; ks < 2; ks++) {
            v8bf a0 = *(const v8bf*)&As[wr + fr][ks*32 + fc];
            v8bf a1 = *(const v8bf*)&As[wr + 16 + fr][ks*32 + fc];
            v8bf b0 = *(const v8bf*)&Bs[wc + fr][ks*32 + fc];
            v8bf b1 = *(const v8bf*)&Bs[wc + 16 + fr][ks*32 + fc];
            acc[0][0] = __builtin_amdgcn_mfma_f32_16x16x32_bf16(a0, b0, acc[0][0], 0, 0, 0);
            acc[0][1] = __builtin_amdgcn_mfma_f32_16x16x32_bf16(a0, b1, acc[0][1], 0, 0, 0);
            acc[1][0] = __builtin_amdgcn_mfma_f32_16x16x32_bf16(a1, b0, acc[1][0], 0, 0, 0);
            acc[1][1] = __builtin_amdgcn_mfma_f32_16x16x32_bf16(a1, b1, acc[1][1], 0, 0, 0);
        }
        __syncthreads();
    }
    int mrow = (lane >> 4) * 4;
    float lv[2][4];
    #pragma unroll
    for (int mi = 0; mi < 2; mi++) {
        int ibase = i0 + wr + mi*16 + mrow;
        float4 l4 = *(const float4*)&linv[(size_t)h*768 + ibase];
        lv[mi][0] = l4.x; lv[mi][1] = l4.y; lv[mi][2] = l4.z; lv[mi][3] = l4.w;
    }
    if (nd0 < 128) {
        #pragma unroll
        for (int mi = 0; mi < 2; mi++) {
            #pragma unroll
            for (int ni = 0; ni < 2; ni++) {
                int d = nd0 + wc + ni*16 + fr;
                #pragma unroll
                for (int rr = 0; rr < 4; rr++) {
                    int i = i0 + wr + mi*16 + mrow + rr;
                    concat[(size_t)i*CONCAT + h*128 + d] = f2bf(acc[mi][ni][rr] * lv[mi][rr]);
                }
            }
        }
    } else {
        float* opt_s = (float*)&As[0][0];
        #pragma unroll
        for (int mi = 0; mi < 2; mi++) {
            #pragma unroll
            for (int ni = 0; ni < 2; ni++) {
                int c = wc + ni*16 + fr;
                if (c < 36) {
                    #pragma unroll
                    for (int rr = 0; rr < 4; rr++) {
                        int rl = wr + mi*16 + mrow + rr;
                        opt_s[rl*36 + c] = acc[mi][ni][rr] * lv[mi][rr];
                    }
                }
            }
        }
        __syncthreads();
        for (int it = tid; it < 768; it += 256) {
            int rl = it / 12, pp = it % 12;
            int i = i0 + rl;
            const float* R = rot + i*9;
            const float* T = trans + i*3;
            float y0 = opt_s[rl*36 + pp*3 + 0] - T[0];
            float y1 = opt_s[rl*36 + pp*3 + 1] - T[1];
            float y2 = opt_s[rl*36 + pp*3 + 2] - T[2];
            float o0 = R[0]*y0 + R[3]*y1 + R[6]*y2;
            float o1 = R[1]*y0 + R[4]*y1 + R[7]*y2;
            float o2 = R[2]*y0 + R[5]*y1 + R[8]*y2;
            float nrm = sqrtf(o0*o0 + o1*o1 + o2*o2 + 1e-8f);
            int hp = h*12 + pp;
            unsigned short* cb = concat + (size_t)i*CONCAT;
            cb[1024 +   0 + hp] = f2bf(o0);
            cb[1024 +  96 + hp] = f2bf(o1);
            cb[1024 + 192 + hp] = f2bf(o2);
            cb[1312 + hp] = f2bf(nrm);
        }
    }
}

// ---------------------------------------------------------------------------
// tail: LN1 + transition MLP (3 MFMA stages) + LN2 + upd + frame, row-local.
// ---------------------------------------------------------------------------
__global__ __launch_bounds__(256) void tail_kernel(
    const float* __restrict__ s, const float* __restrict__ ipa,
    const float* __restrict__ bo,
    const float* __restrict__ g1, const float* __restrict__ be1,
    const unsigned short* __restrict__ Wt1, const float* __restrict__ bt1,
    const unsigned short* __restrict__ Wt2, const float* __restrict__ bt2,
    const unsigned short* __restrict__ Wt3, const float* __restrict__ bt3,
    const float* __restrict__ g2, const float* __restrict__ be2,
    const float* __restrict__ Wbb, const float* __restrict__ bbb,
    const float* __restrict__ mask,
    const float* __restrict__ rot, const float* __restrict__ trans,
    float* __restrict__ out, float* __restrict__ rot_out, float* __restrict__ trans_out)
{
    __shared__ float s1f[32][257];
    __shared__ unsigned short Ab[32][264];
    __shared__ float upd_s[32][6];
    int i0 = blockIdx.x * 32;
    int tid = threadIdx.x, lane = tid & 63, wid = tid >> 6;
    int fr = lane & 15, fc = (lane >> 4) * 8, mrow = (lane >> 4) * 4;

    // ---- LN1: x = s + ipa + bo ----
    int r = tid >> 3, cg = (tid & 7) * 32;
    {
        float xv[32];
        float sum = 0.f, sq = 0.f;
        #pragma unroll
        for (int q = 0; q < 8; q++) {
            float4 a = *(const float4*)&s[(size_t)(i0 + r)*256 + cg + q*4];
            float4 b = *(const float4*)&ipa[(size_t)(i0 + r)*256 + cg + q*4];
            float4 c = *(const float4*)&bo[cg + q*4];
            float v0 = a.x + b.x + c.x, v1 = a.y + b.y + c.y;
            float v2 = a.z + b.z + c.z, v3 = a.w + b.w + c.w;
            xv[q*4+0] = v0; xv[q*4+1] = v1; xv[q*4+2] = v2; xv[q*4+3] = v3;
            sum += v0 + v1 + v2 + v3;
            sq  += v0*v0 + v1*v1 + v2*v2 + v3*v3;
        }
        #pragma unroll
        for (int d = 1; d < 8; d <<= 1) { sum += __shfl_xor(sum, d); sq += __shfl_xor(sq, d); }
        float mu = sum * (1.0f/256.0f);
        float var = sq * (1.0f/256.0f) - mu*mu;
        float rsig = 1.0f / sqrtf(var + 1e-5f);
        #pragma unroll
        for (int c = 0; c < 32; c++) {
            float o = (xv[c] - mu) * rsig * g1[cg + c] + be1[cg + c];
            s1f[r][cg + c] = o;
            Ab[r][cg + c] = f2bf(o);
        }
    }
    __syncthreads();

    // ---- 3 GEMM stages ----
    const unsigned short* Ws[3] = {Wt1, Wt2, Wt3};
    const float* Bs[3] = {bt1, bt2, bt3};
    #pragma unroll
    for (int stage = 0; stage < 3; stage++) {
        const unsigned short* W = Ws[stage];
        const float* bias = Bs[stage];
        v4f acc[2][4] = {};
        #pragma unroll
        for (int k0 = 0; k0 < 8; k0++) {
            v8bf a0 = *(const v8bf*)&Ab[fr][k0*32 + fc];
            v8bf a1 = *(const v8bf*)&Ab[16 + fr][k0*32 + fc];
            #pragma unroll
            for (int n = 0; n < 4; n++) {
                int d = wid*64 + n*16 + fr;
                v8bf b = *(const v8bf*)&W[(size_t)d*256 + k0*32 + fc];
                acc[0][n] = __builtin_amdgcn_mfma_f32_16x16x32_bf16(a0, b, acc[0][n], 0, 0, 0);
                acc[1][n] = __builtin_amdgcn_mfma_f32_16x16x32_bf16(a1, b, acc[1][n], 0, 0, 0);
            }
        }
        __syncthreads();
        if (stage < 2) {
            #pragma unroll
            for (int mi = 0; mi < 2; mi++) {
                #pragma unroll
                for (int n = 0; n < 4; n++) {
                    int d = wid*64 + n*16 + fr;
                    #pragma unroll
                    for (int rr = 0; rr < 4; rr++) {
                        int m = mi*16 + mrow + rr;
                        Ab[m][d] = f2bf(fmaxf(acc[mi][n][rr] + bias[d], 0.f));
                    }
                }
            }
        } else {
            #pragma unroll
            for (int mi = 0; mi < 2; mi++) {
                #pragma unroll
                for (int n = 0; n < 4; n++) {
                    int d = wid*64 + n*16 + fr;
                    #pragma unroll
                    for (int rr = 0; rr < 4; rr++) {
                        int m = mi*16 + mrow + rr;
                        s1f[m][d] += acc[mi][n][rr] + bias[d];
                    }
                }
            }
        }
        __syncthreads();
    }

    // ---- LN2 over s1f (now s1 + y3); write out + keep s2 in s1f ----
    {
        float xv[32];
        float sum = 0.f, sq = 0.f;
        #pragma unroll
        for (int c = 0; c < 32; c++) {
            float v = s1f[r][cg + c];
            xv[c] = v; sum += v; sq += v*v;
        }
        #pragma unroll
        for (int d = 1; d < 8; d <<= 1) { sum += __shfl_xor(sum, d); sq += __shfl_xor(sq, d); }
        float mu = sum * (1.0f/256.0f);
        float var = sq * (1.0f/256.0f) - mu*mu;
        float rsig = 1.0f / sqrtf(var + 1e-5f);
        float o4[32];
        #pragma unroll
        for (int c = 0; c < 32; c++)
            o4[c] = (xv[c] - mu) * rsig * g2[cg + c] + be2[cg + c];
        #pragma unroll
        for (int q = 0; q < 8; q++) {
            float4 w; w.x = o4[q*4]; w.y = o4[q*4+1]; w.z = o4[q*4+2]; w.w = o4[q*4+3];
            *(float4*)&out[(size_t)(i0 + r)*256 + cg + q*4] = w;
        }
        __syncthreads();
        #pragma unroll
        for (int c = 0; c < 32; c++) s1f[r][cg + c] = o4[c];
    }
    __syncthreads();

    // ---- upd = (s2 @ Wbb^T + bbb) * mask ----
    if (tid < 192) {
        int rr = tid / 6, d = tid % 6;
        float acc = bbb[d];
        const float* wb = Wbb + d*256;
        #pragma unroll 8
        for (int c = 0; c < 256; c++) acc += s1f[rr][c] * wb[c];
        upd_s[rr][d] = acc * mask[i0 + rr];
    }
    __syncthreads();

    // ---- frame composition ----
    if (tid < 32) {
        int i = i0 + tid;
        float u0 = upd_s[tid][0], u1 = upd_s[tid][1], u2 = upd_s[tid][2];
        float t0 = upd_s[tid][3], t1 = upd_s[tid][4], t2 = upd_s[tid][5];
        float n = sqrtf(1.f + u0*u0 + u1*u1 + u2*u2);
        float w = 1.f/n, x = u0/n, y = u1/n, z = u2/n;
        float R[3][3];
        R[0][0] = 1.f - 2.f*(y*y + z*z); R[0][1] = 2.f*(x*y - w*z);       R[0][2] = 2.f*(x*z + w*y);
        R[1][0] = 2.f*(x*y + w*z);       R[1][1] = 1.f - 2.f*(x*x + z*z); R[1][2] = 2.f*(y*z - w*x);
        R[2][0] = 2.f*(x*z - w*y);       R[2][1] = 2.f*(y*z + w*x);       R[2][2] = 1.f - 2.f*(x*x + y*y);
        const float* Ri = rot + i*9;
        #pragma unroll
        for (int a = 0; a < 3; a++) {
            #pragma unroll
            for (int b = 0; b < 3; b++) {
                float acc = 0.f;
                #pragma unroll
                for (int j = 0; j < 3; j++) acc += Ri[a*3+j]*R[j][b];
                rot_out[i*9 + a*3 + b] = acc;
            }
            trans_out[i*3 + a] = trans[i*3 + a] + Ri[a*3+0]*t0 + Ri[a*3+1]*t1 + Ri[a*3+2]*t2;
        }
    }
}

// ---------------------------------------------------------------------------
extern "C" void kernel_launch(void* const* d_in, const int* in_sizes, int n_in,
                              void* d_out, int out_size, void* d_ws, size_t ws_size,
                              hipStream_t stream)
{
    const float* s      = (const float*)d_in[0];
    const float* p      = (const float*)d_in[1];
    const float* rot    = (const float*)d_in[2];
    const float* trans  = (const float*)d_in[3];
    const float* mask   = (const float*)d_in[4];
    const float* Wq     = (const float*)d_in[5];
    const float* bq     = (const float*)d_in[6];
    const float* Wkv    = (const float*)d_in[7];
    const float* bkv    = (const float*)d_in[8];
    const float* Wqp    = (const float*)d_in[9];
    const float* bqp    = (const float*)d_in[10];
    const float* Wkvp   = (const float*)d_in[11];
    const float* bkvp   = (const float*)d_in[12];
    const float* Wpb    = (const float*)d_in[13];
    const float* bpb    = (const float*)d_in[14];
    const float* Wo     = (const float*)d_in[15];
    const float* bo     = (const float*)d_in[16];
    const float* Wt1    = (const float*)d_in[17];
    const float* bt1    = (const float*)d_in[18];
    const float* Wt2    = (const float*)d_in[19];
    const float* bt2    = (const float*)d_in[20];
    const float* Wt3    = (const float*)d_in[21];
    const float* bt3    = (const float*)d_in[22];
    const float* Wbb    = (const float*)d_in[23];
    const float* bbb    = (const float*)d_in[24];
    const float* head_w = (const float*)d_in[25];
    const float* g1     = (const float*)d_in[26];
    const float* be1    = (const float*)d_in[27];
    const float* g2     = (const float*)d_in[28];
    const float* be2    = (const float*)d_in[29];

    float* out = (float*)d_out;
    char*  wsb = (char*)d_ws;

    size_t off = 0;
    auto alloc = [&](size_t bytes) -> char* {
        char* ptr = wsb + off;
        off += (bytes + 255) & ~(size_t)255;
        return ptr;
    };
    float* qpraw   = (float*)alloc((size_t)NN*192*4);
    float* kvpraw  = (float*)alloc((size_t)NN*480*4);
    float* att     = (float*)alloc((size_t)8*768*768*4);
    float* ipa     = (float*)alloc((size_t)NN*256*4);
    float* linv    = (float*)alloc((size_t)8*768*4);
    float* lpart   = (float*)alloc((size_t)16*768*4);
    float* opart   = (float*)alloc((size_t)2*768*1024*4);
    unsigned* m0enc = (unsigned*)alloc((size_t)8*768*4);
    unsigned short* s_bf    = (unsigned short*)alloc((size_t)NN*256*2);
    unsigned short* Wq_bf   = (unsigned short*)alloc((size_t)1024*256*2);
    unsigned short* Wkv_bf  = (unsigned short*)alloc((size_t)2048*256*2);
    unsigned short* Wqp_bf  = (unsigned short*)alloc((size_t)192*256*2);
    unsigned short* Wkvp_bf = (unsigned short*)alloc((size_t)480*256*2);
    unsigned short* Wo_bf   = (unsigned short*)alloc((size_t)256*2432*2);
    unsigned short* Wt1_bf  = (unsigned short*)alloc((size_t)256*256*2);
    unsigned short* Wt2_bf  = (unsigned short*)alloc((size_t)256*256*2);
    unsigned short* Wt3_bf  = (unsigned short*)alloc((size_t)256*256*2);
    unsigned short* q_bf    = (unsigned short*)alloc((size_t)NN*1024*2);
    unsigned short* kv_bf   = (unsigned short*)alloc((size_t)NN*2048*2);
    unsigned short* qph     = (unsigned short*)alloc((size_t)NN*256*2);
    unsigned short* qpl     = (unsigned short*)alloc((size_t)NN*256*2);
    unsigned short* kph     = (unsigned short*)alloc((size_t)NN*256*2);
    unsigned short* kpl     = (unsigned short*)alloc((size_t)NN*256*2);
    unsigned short* Vc      = (unsigned short*)alloc((size_t)8*192*768*2);
    unsigned short* att_bf  = (unsigned short*)alloc((size_t)8*768*768*2);
    unsigned short* concat  = (unsigned short*)alloc((size_t)NN*CONCAT*2);

    // 0) zero-init atomic targets
    hipMemsetAsync(ipa, 0, (size_t)NN*256*4, stream);
    hipMemsetAsync(m0enc, 0, (size_t)8*768*4, stream);

    // 1) f32->bf16 conversions
    CvtDesc cd;
    const float* csrc[NCVT]    = {s, Wq, Wkv, Wqp, Wkvp, Wo, Wt1, Wt2, Wt3};
    unsigned short* cdst[NCVT] = {s_bf, Wq_bf, Wkv_bf, Wqp_bf, Wkvp_bf, Wo_bf, Wt1_bf, Wt2_bf, Wt3_bf};
    int csz[NCVT] = {NN*256, 1024*256, 2048*256, 192*256, 480*256, 256*2432, 256*256, 256*256, 256*256};
    int cum = 0;
    for (int i2 = 0; i2 < NCVT; i2++) {
        cd.src[i2] = csrc[i2]; cd.dst[i2] = cdst[i2]; cd.nelem[i2] = csz[i2];
        cd.blk_start[i2] = cum;
        cum += (csz[i2] + 2047) / 2048;
    }
    cd.blk_start[NCVT] = cum;
    cvt_many<<<cum, 256, 0, stream>>>(cd);

    // 2) All projections in one GEMM launch
    ProjDesc pd;
    pd.W[0] = Wq_bf;   pd.bias[0] = bq;   pd.dstb[0] = q_bf;   pd.dstf[0] = nullptr; pd.D[0] = 1024; pd.ldc[0] = 1024; pd.mode[0] = 2;
    pd.W[1] = Wkv_bf;  pd.bias[1] = bkv;  pd.dstb[1] = kv_bf;  pd.dstf[1] = nullptr; pd.D[1] = 2048; pd.ldc[1] = 2048; pd.mode[1] = 2;
    pd.W[2] = Wqp_bf;  pd.bias[2] = bqp;  pd.dstb[2] = nullptr; pd.dstf[2] = qpraw;  pd.D[2] = 192;  pd.ldc[2] = 192;  pd.mode[2] = 0;
    pd.W[3] = Wkvp_bf; pd.bias[3] = bkvp; pd.dstb[3] = nullptr; pd.dstf[3] = kvpraw; pd.D[3] = 480;  pd.ldc[3] = 480;  pd.mode[3] = 0;
    pd.blk_start[0] = 0; pd.blk_start[1] = 16; pd.blk_start[2] = 48; pd.blk_start[3] = 51; pd.blk_start[4] = 59;
    proj_all<<<dim3(59, 12), 256, 0, stream>>>(s_bf, pd);

    // 3) rotate + vtrans merged
    prep2_kernel<<<672 + 192, 256, 0, stream>>>(
        qpraw, kvpraw, rot, trans, kv_bf, qph, qpl, kph, kpl, Vc);

    // 4) logits (+row max via atomicMax)
    logits_mfma<<<dim3(12, 12, 8), 256, 0, stream>>>(
        q_bf, kv_bf, qph, qpl, kph, kpl, mask, head_w, att, m0enc);

    // 5) single-pass p kernel, split over 2 j-halves
    fused_p3s_kernel<<<dim3(768, 2), 256, 0, stream>>>(
        att, p, Wpb, bpb, m0enc, att_bf, lpart, opart);
    preduce_kernel<<<768, 256, 0, stream>>>(lpart, opart, linv, concat);

    // 6) o / opt (+final epilogue)
    attvc_mfma<<<dim3(3, 12, 8), 256, 0, stream>>>(att_bf, Vc, linv, rot, trans, concat);

    // 7) Output projection (split-K into zeroed ipa)
    mfma_gemm<4,0,0><<<dim3(4,12,4), 256, 0, stream>>>(concat, Wo_bf, nullptr, ipa, nullptr, 256, 2432, 256);

    // 8) fused tail: LN1 + MLP + LN2 + upd + frame
    tail_kernel<<<24, 256, 0, stream>>>(
        s, ipa, bo, g1, be1, Wt1_bf, bt1, Wt2_bf, bt2, Wt3_bf, bt3,
        g2, be2, Wbb, bbb, mask, rot, trans,
        out, out + (size_t)NN*256, out + (size_t)NN*256 + (size_t)NN*9);
}